// Round 11
// baseline (1450.309 us; speedup 1.0000x reference)
//
#include <hip/hip_runtime.h>

// GConvLSTM single step x4 layers, H=C=0 => f-gate dead, peepholes dead.
// bf16 storage; SpMV = R5/R10 best build (8B Edge{src,w}, unroll x4, no NT).
// MFMA chebgate v4: no-LDS direct A-frags (proven best) + 64-f column tiles:
//   A re-reads 5->3 (L3, FPAD 160->192 zero-padded) and 2->1 (L2).
//   acc [2][4][3] f32x4 (~130 VGPR, ~3 waves/SIMD — clear of R8's 1-block cliff).

#define IN_CH 10
typedef unsigned short u16;
typedef unsigned long long u64;
typedef short bf16x8 __attribute__((ext_vector_type(8)));
typedef float f32x4 __attribute__((ext_vector_type(4)));

struct __align__(8) Edge { int s; float w; };

__device__ __forceinline__ float bf2f(u16 u) { return __uint_as_float(((unsigned)u) << 16); }
__device__ __forceinline__ float lo16f(unsigned v) { return __uint_as_float(v << 16); }
__device__ __forceinline__ float hi16f(unsigned v) { return __uint_as_float(v & 0xffff0000u); }
__device__ __forceinline__ u16 f2bf(float f) {
    unsigned x = __float_as_uint(f);
    return (u16)((x + 0x7fff + ((x >> 16) & 1)) >> 16);  // RNE
}
__device__ __forceinline__ float ldv(const float* p) { return *p; }
__device__ __forceinline__ float ldv(const u16* p) { return bf2f(*p); }
__device__ __forceinline__ void stv(float* p, float v) { *p = v; }
__device__ __forceinline__ void stv(u16* p, float v) { *p = f2bf(v); }

// ---------------- graph preprocessing ----------------

__global__ void k_count(const int* __restrict__ dst, int* __restrict__ cnt, int e) {
    int i = blockIdx.x * 256 + threadIdx.x;
    if (i < e) atomicAdd(&cnt[dst[i]], 1);
}

__global__ void k_dinv(const int* __restrict__ cnt, float* __restrict__ dinv, int n) {
    int i = blockIdx.x * 256 + threadIdx.x;
    if (i < n) dinv[i] = cnt[i] > 0 ? rsqrtf((float)cnt[i]) : 0.f;
}

__global__ __launch_bounds__(1024) void k_scan(const int* __restrict__ cnt,
                                               int* __restrict__ row_ptr, int n) {
    __shared__ int sums[1024];
    int t = threadIdx.x;
    int chunk = (n + 1023) >> 10;
    int lo = t * chunk;
    int hi = lo + chunk < n ? lo + chunk : n;
    int s = 0;
    for (int i = lo; i < hi; i++) s += cnt[i];
    sums[t] = s;
    __syncthreads();
    for (int off = 1; off < 1024; off <<= 1) {
        int v = (t >= off) ? sums[t - off] : 0;
        __syncthreads();
        sums[t] += v;
        __syncthreads();
    }
    int prefix = (t == 0) ? 0 : sums[t - 1];
    for (int i = lo; i < hi; i++) { row_ptr[i] = prefix; prefix += cnt[i]; }
    if (t == 0) row_ptr[n] = sums[1023];
}

__global__ void k_copy_i32(const int* __restrict__ a, int* __restrict__ b, int n) {
    int i = blockIdx.x * 256 + threadIdx.x;
    if (i < n) b[i] = a[i];
}

__global__ void k_fill(const int* __restrict__ src, const int* __restrict__ dst,
                       const float* __restrict__ dinv, int* __restrict__ cursor,
                       Edge* __restrict__ ed, int e) {
    int i = blockIdx.x * 256 + threadIdx.x;
    if (i >= e) return;
    int s = src[i], d = dst[i];
    int pos = atomicAdd(&cursor[d], 1);
    float w = dinv[s] * dinv[d];
    u64 v = (u64)(unsigned)s | ((u64)__float_as_uint(w) << 32);
    *(u64*)&ed[pos] = v;  // single 8B store
}

// ---------------- Cheb SpMV: full row, unroll x4 ----------------

template <int F>
__global__ void k_spmv(const u16* __restrict__ X, const u16* __restrict__ Tprev,
                       u16* __restrict__ Tout, const int* __restrict__ row_ptr,
                       const Edge* __restrict__ ed, int n, float scale) {
    int lane = threadIdx.x;  // [0, F/2)
    int node = blockIdx.x * blockDim.y + threadIdx.y;
    if (node >= n) return;
    int lo = row_ptr[node], hi = row_ptr[node + 1];
    const u16* Xc = X + 2 * lane;
    float a0 = 0.f, a1 = 0.f, b0 = 0.f, b1 = 0.f;
    float c0 = 0.f, c1 = 0.f, d0 = 0.f, d1 = 0.f;
    int e = lo;
    for (; e + 4 <= hi; e += 4) {
        Edge e0 = ed[e], e1 = ed[e + 1], e2 = ed[e + 2], e3 = ed[e + 3];
        unsigned v0 = *(const unsigned*)(Xc + (size_t)e0.s * F);
        unsigned v1 = *(const unsigned*)(Xc + (size_t)e1.s * F);
        unsigned v2 = *(const unsigned*)(Xc + (size_t)e2.s * F);
        unsigned v3 = *(const unsigned*)(Xc + (size_t)e3.s * F);
        a0 = fmaf(e0.w, lo16f(v0), a0); a1 = fmaf(e0.w, hi16f(v0), a1);
        b0 = fmaf(e1.w, lo16f(v1), b0); b1 = fmaf(e1.w, hi16f(v1), b1);
        c0 = fmaf(e2.w, lo16f(v2), c0); c1 = fmaf(e2.w, hi16f(v2), c1);
        d0 = fmaf(e3.w, lo16f(v3), d0); d1 = fmaf(e3.w, hi16f(v3), d1);
    }
    for (; e < hi; e++) {
        Edge e0 = ed[e];
        unsigned v0 = *(const unsigned*)(Xc + (size_t)e0.s * F);
        a0 = fmaf(e0.w, lo16f(v0), a0); a1 = fmaf(e0.w, hi16f(v0), a1);
    }
    float v0 = -scale * ((a0 + b0) + (c0 + d0));
    float v1 = -scale * ((a1 + b1) + (c1 + d1));
    if (Tprev) {
        unsigned pv = *(const unsigned*)(Tprev + (size_t)node * F + 2 * lane);
        v0 -= lo16f(pv);
        v1 -= hi16f(pv);
    }
    *(unsigned*)(Tout + (size_t)node * F + 2 * lane) =
        (unsigned)f2bf(v0) | ((unsigned)f2bf(v1) << 16);
}

// ---------------- VALU chebgate (layers 0,1) ----------------
struct TP { const void* p[5]; };

template <typename ST, int FIN, int K>
__global__ __launch_bounds__(256) void k_chebgate(TP tp, const float* __restrict__ Wp,
                                                  const float* __restrict__ b4,
                                                  ST* __restrict__ H, int n, int F,
                                                  int F4pad) {
    __shared__ float As[FIN][68];
    __shared__ float Ws[FIN][128];
    const int tid = threadIdx.x;
    const int fx = tid & 31, ry = tid >> 5;
    const int row0 = blockIdx.y * 64;
    const int f0 = blockIdx.x * 32;
    const int f = f0 + fx;

    float acc[8][3];
    const float4 bv = *(const float4*)&b4[(size_t)f * 4];
#pragma unroll
    for (int r = 0; r < 8; r++) { acc[r][0] = bv.x; acc[r][1] = bv.y; acc[r][2] = bv.z; }

#pragma unroll
    for (int t = 0; t < K; t++) {
        const ST* T = (const ST*)tp.p[t];
        for (int idx = tid; idx < 64 * FIN; idx += 256) {
            int r = idx / FIN, a = idx - r * FIN;
            int rr = row0 + r;
            if (rr >= n) rr = n - 1;
            As[a][r] = ldv(&T[(size_t)rr * FIN + a]);
        }
        const float* Wt = Wp + (size_t)t * FIN * F4pad + (size_t)f0 * 4;
        for (int idx = tid; idx < FIN * 128; idx += 256) {
            int aa = idx >> 7, c = idx & 127;
            Ws[aa][c] = Wt[(size_t)aa * F4pad + c];
        }
        __syncthreads();
#pragma unroll 2
        for (int a = 0; a < FIN; a++) {
            const float4 w = *(const float4*)&Ws[a][fx * 4];
            const float4 x0 = *(const float4*)&As[a][ry * 8];
            const float4 x1 = *(const float4*)&As[a][ry * 8 + 4];
            const float xr[8] = {x0.x, x0.y, x0.z, x0.w, x1.x, x1.y, x1.z, x1.w};
#pragma unroll
            for (int r = 0; r < 8; r++) {
                acc[r][0] = fmaf(xr[r], w.x, acc[r][0]);
                acc[r][1] = fmaf(xr[r], w.y, acc[r][1]);
                acc[r][2] = fmaf(xr[r], w.z, acc[r][2]);
            }
        }
        __syncthreads();
    }

    if (f < F) {
#pragma unroll
        for (int r = 0; r < 8; r++) {
            int row = row0 + ry * 8 + r;
            if (row < n) {
                float gi = 1.f / (1.f + __expf(-acc[r][0]));
                float go = 1.f / (1.f + __expf(-acc[r][2]));
                float c = gi * tanhf(acc[r][1]);
                float h = go * tanhf(c);
                stv(&H[(size_t)row * F + f], fmaxf(h, 0.f));
            }
        }
    }
}

// ---------------- MFMA chebgate v4 (layers 2,3): no LDS, 64-f tiles ----------------
// Block = 4 waves x 32 rows = 128 rows; 64 f-values (4 s-subtiles) x 3 gates.
// A-frag: direct global load; B: Wt[col][k], col = g*FPAD + f0 + s*16 + ln.
// C/D: col=lane&15, row=(lane>>4)*4+reg.

template <int FIN, int K, int FPAD>
__global__ __launch_bounds__(256) void k_chebgate_mfma(TP tp, const u16* __restrict__ Wt,
                                                       const float* __restrict__ b3,
                                                       u16* __restrict__ H, int n, int F,
                                                       int Hstride) {
    constexpr int KT = K * FIN;
    const int wave = threadIdx.x >> 6;
    const int lane = threadIdx.x & 63;
    const int r0 = blockIdx.x * 128 + wave * 32;
    const int f0 = blockIdx.y * 64;
    const int ln = lane & 15;
    const int lk = lane >> 4;

    f32x4 acc[2][4][3];
#pragma unroll
    for (int rt = 0; rt < 2; rt++)
#pragma unroll
        for (int s = 0; s < 4; s++)
#pragma unroll
            for (int g = 0; g < 3; g++) acc[rt][s][g] = (f32x4){0.f, 0.f, 0.f, 0.f};

    int arow[2];
#pragma unroll
    for (int rt = 0; rt < 2; rt++) {
        int row = r0 + rt * 16 + ln;
        arow[rt] = row < n ? row : n - 1;
    }

    for (int k0 = 0; k0 < KT; k0 += 32) {
        const int t = k0 / FIN;
        const int a0 = k0 % FIN;
        const u16* T = (const u16*)tp.p[t];
        bf16x8 af[2];
#pragma unroll
        for (int rt = 0; rt < 2; rt++)
            af[rt] = *(const bf16x8*)(T + (size_t)arow[rt] * FIN + a0 + lk * 8);
#pragma unroll
        for (int s = 0; s < 4; s++) {
#pragma unroll
            for (int g = 0; g < 3; g++) {
                int col = g * FPAD + f0 + s * 16 + ln;
                bf16x8 bf = *(const bf16x8*)(Wt + (size_t)col * KT + k0 + lk * 8);
#pragma unroll
                for (int rt = 0; rt < 2; rt++)
                    acc[rt][s][g] = __builtin_amdgcn_mfma_f32_16x16x32_bf16(
                        af[rt], bf, acc[rt][s][g], 0, 0, 0);
            }
        }
    }

#pragma unroll
    for (int s = 0; s < 4; s++) {
        int fcol = f0 + s * 16 + ln;
        if (fcol >= F) continue;
        float bi = b3[0 * FPAD + fcol];
        float bc = b3[1 * FPAD + fcol];
        float bo = b3[2 * FPAD + fcol];
#pragma unroll
        for (int rt = 0; rt < 2; rt++) {
#pragma unroll
            for (int reg = 0; reg < 4; reg++) {
                int row = r0 + rt * 16 + lk * 4 + reg;
                if (row < n) {
                    float gi = 1.f / (1.f + __expf(-(acc[rt][s][0][reg] + bi)));
                    float go = 1.f / (1.f + __expf(-(acc[rt][s][2][reg] + bo)));
                    float c = gi * tanhf(acc[rt][s][1][reg] + bc);
                    float h = go * tanhf(c);
                    H[(size_t)row * Hstride + fcol] = f2bf(fmaxf(h, 0.f));
                }
            }
        }
    }
}

// ---------------- weight/bias packing ----------------

__global__ void k_pack_w(const float* __restrict__ Wi, const float* __restrict__ Wc,
                         const float* __restrict__ Wo, float* __restrict__ Wp,
                         int KFIN, int F, int F4pad) {
    int idx = blockIdx.x * 256 + threadIdx.x;
    int tot = KFIN * F4pad;
    if (idx >= tot) return;
    int c = idx % F4pad;
    int ka = idx / F4pad;
    int f = c >> 2, g = c & 3;
    float v = 0.f;
    if (g < 3 && f < F) {
        const float* Wg = (g == 0) ? Wi : ((g == 1) ? Wc : Wo);
        v = Wg[(size_t)ka * F + f];
    }
    Wp[idx] = v;
}

__global__ void k_pack_b(const float* __restrict__ bxi, const float* __restrict__ bhi,
                         const float* __restrict__ bi, const float* __restrict__ bxc,
                         const float* __restrict__ bhc, const float* __restrict__ bc,
                         const float* __restrict__ bxo, const float* __restrict__ bho,
                         const float* __restrict__ bo, float* __restrict__ b4,
                         int F, int F4pad) {
    int idx = blockIdx.x * 256 + threadIdx.x;
    if (idx >= F4pad) return;
    int f = idx >> 2, g = idx & 3;
    float v = 0.f;
    if (g < 3 && f < F) {
        if (g == 0) v = bxi[f] + bhi[f] + bi[f];
        else if (g == 1) v = bxc[f] + bhc[f] + bc[f];
        else v = bxo[f] + bho[f] + bo[f];
    }
    b4[idx] = v;
}

__global__ void k_pack_wt(const float* __restrict__ Wi, const float* __restrict__ Wc,
                          const float* __restrict__ Wo, u16* __restrict__ Wt,
                          int KT, int Fin, int F, int FPAD) {
    int idx = blockIdx.x * 256 + threadIdx.x;
    int tot = 3 * FPAD * KT;
    if (idx >= tot) return;
    int k = idx % KT;
    int col = idx / KT;
    int g = col / FPAD, f = col % FPAD;
    int t = k / Fin, a = k % Fin;
    float v = 0.f;
    if (f < F) {
        const float* Wg = (g == 0) ? Wi : ((g == 1) ? Wc : Wo);
        v = Wg[((size_t)t * Fin + a) * F + f];
    }
    Wt[idx] = f2bf(v);
}

__global__ void k_pack_b3(const float* __restrict__ bxi, const float* __restrict__ bhi,
                          const float* __restrict__ bi, const float* __restrict__ bxc,
                          const float* __restrict__ bhc, const float* __restrict__ bc,
                          const float* __restrict__ bxo, const float* __restrict__ bho,
                          const float* __restrict__ bo, float* __restrict__ b3,
                          int F, int FPAD) {
    int idx = blockIdx.x * 256 + threadIdx.x;
    if (idx >= 3 * FPAD) return;
    int g = idx / FPAD, f = idx % FPAD;
    float v = 0.f;
    if (f < F) {
        if (g == 0) v = bxi[f] + bhi[f] + bi[f];
        else if (g == 1) v = bxc[f] + bhc[f] + bc[f];
        else v = bxo[f] + bho[f] + bo[f];
    }
    b3[idx] = v;
}

__global__ void k_cvt(const float* __restrict__ x, u16* __restrict__ y, int n) {
    int i = blockIdx.x * 256 + threadIdx.x;
    if (i < n) y[i] = f2bf(x[i]);
}

// ---------------- final linear + softmax ----------------
__global__ void k_final(const u16* __restrict__ H, const float* __restrict__ W,
                        const float* __restrict__ b, float* __restrict__ out, int n) {
    int gtid = blockIdx.x * blockDim.x + threadIdx.x;
    int node = gtid >> 6;
    int lane = threadIdx.x & 63;
    if (node >= n) return;
    const u16* h = H + (size_t)node * 152;
    float l0 = 0.f, l1 = 0.f;
    for (int f = lane; f < 152; f += 64) {
        float hv = bf2f(h[f]);
        l0 = fmaf(hv, W[f * 2 + 0], l0);
        l1 = fmaf(hv, W[f * 2 + 1], l1);
    }
#pragma unroll
    for (int off = 32; off > 0; off >>= 1) {
        l0 += __shfl_down(l0, off);
        l1 += __shfl_down(l1, off);
    }
    if (lane == 0) {
        l0 += b[0];
        l1 += b[1];
        float m = fmaxf(l0, l1);
        float e0 = __expf(l0 - m), e1 = __expf(l1 - m);
        float s = 1.f / (e0 + e1);
        out[(size_t)node * 2 + 0] = e0 * s;
        out[(size_t)node * 2 + 1] = e1 * s;
    }
}

// ---------------- launch ----------------

static inline size_t al(size_t x) { return (x + 255) & ~(size_t)255; }

extern "C" void kernel_launch(void* const* d_in, const int* in_sizes, int n_in,
                              void* d_out, int out_size, void* d_ws, size_t ws_size,
                              hipStream_t stream) {
    const float* X0 = (const float*)d_in[0];
    const int* ei = (const int*)d_in[1];
    const int N = in_sizes[0] / IN_CH;
    const int E = in_sizes[1] / 2;
    const int* src = ei;
    const int* dst = ei + E;

    // ---- workspace carve (~122 MB) ----
    char* p = (char*)d_ws;
    size_t off = 0;
    auto carve = [&](size_t bytes) -> char* { char* r = p + off; off += al(bytes); return r; };
    int* row_ptr  = (int*)carve((size_t)(N + 1) * 4);
    int* cnt      = (int*)carve((size_t)N * 4);   // doubles as cursor
    float* dinv   = (float*)carve((size_t)N * 4);
    Edge* edges   = (Edge*)carve((size_t)E * 8);
    const size_t S64 = al((size_t)N * 64 * 2);
    char* bufA    = carve(5 * S64);               // 64 MB
    char* bufB    = carve((size_t)N * 304);       // 30.4 MB
    float* Wp     = (float*)carve((size_t)48 * 128 * 4);
    float* b4     = (float*)carve((size_t)128 * 4);
    u16* Wt       = (u16*)carve((size_t)576 * 320 * 2);  // 3*FPAD(192) x KT(320)
    float* b3     = (float*)carve((size_t)576 * 4);
    (void)ws_size;

    u16* X0c  = (u16*)bufA;                                   // N x 10
    u16* T0_1 = (u16*)(bufA + al((size_t)N * 20));            // N x 10
    u16* H0   = (u16*)(bufA + S64);                           // N x 16
    u16* T1_1 = (u16*)(bufA + S64 + al((size_t)N * 32));      // N x 16
    u16* T1_2 = (u16*)(bufA + S64 + 2 * al((size_t)N * 32));  // N x 16
    u16* L2T[4];
    for (int t = 0; t < 4; t++) L2T[t] = (u16*)(bufB + t * al((size_t)N * 64));
    u16* L3T[5];
    for (int t = 0; t < 5; t++) L3T[t] = (u16*)(bufA + t * S64);
    u16* Hfin = (u16*)bufB;                                   // N x 152

    // ---- graph preprocessing ----
    int gE = (E + 255) / 256, gN = (N + 255) / 256;
    hipMemsetAsync(cnt, 0, (size_t)N * 4, stream);
    k_count<<<gE, 256, 0, stream>>>(dst, cnt, E);
    k_dinv<<<gN, 256, 0, stream>>>(cnt, dinv, N);
    k_scan<<<1, 1024, 0, stream>>>(cnt, row_ptr, N);
    k_copy_i32<<<gN, 256, 0, stream>>>(row_ptr, cnt, N);
    k_fill<<<gE, 256, 0, stream>>>(src, dst, dinv, cnt, edges, E);

    k_cvt<<<(N * IN_CH + 255) / 256, 256, 0, stream>>>(X0, X0c, N * IN_CH);

    dim3 gv(1, (N + 63) / 64);
    int rb = (N + 127) / 128;

    // spmv shapes: LPN = F/2 lanes per node
    dim3 bs5(5, 48);   int g5 = (N + 47) / 48;
    dim3 bs8(8, 32);   int g8 = (N + 31) / 32;
    dim3 bs16(16, 16); int g16 = (N + 15) / 16;
    dim3 bs32(32, 8);  int g32 = (N + 7) / 8;

    // ---- layer 0: VALU, K=2, Fin=10, F=16 ----
    {
        k_pack_w<<<(20 * 128 + 255) / 256, 256, 0, stream>>>(
            (const float*)d_in[2], (const float*)d_in[10], (const float*)d_in[14], Wp, 20, 16, 128);
        k_pack_b<<<1, 256, 0, stream>>>(
            (const float*)d_in[3], (const float*)d_in[4], (const float*)d_in[5],
            (const float*)d_in[11], (const float*)d_in[12], (const float*)d_in[13],
            (const float*)d_in[15], (const float*)d_in[16], (const float*)d_in[17], b4, 16, 128);
        k_spmv<10><<<g5, bs5, 0, stream>>>(X0c, nullptr, T0_1, row_ptr, edges, N, 1.f);
        TP tp; tp.p[0] = X0c; tp.p[1] = T0_1;
        k_chebgate<u16, 10, 2><<<gv, 256, 0, stream>>>(tp, Wp, b4, H0, N, 16, 128);
    }
    // ---- layer 1: VALU, K=3, Fin=16, F=32 ----
    {
        k_pack_w<<<(48 * 128 + 255) / 256, 256, 0, stream>>>(
            (const float*)d_in[18], (const float*)d_in[26], (const float*)d_in[30], Wp, 48, 32, 128);
        k_pack_b<<<1, 256, 0, stream>>>(
            (const float*)d_in[19], (const float*)d_in[20], (const float*)d_in[21],
            (const float*)d_in[27], (const float*)d_in[28], (const float*)d_in[29],
            (const float*)d_in[31], (const float*)d_in[32], (const float*)d_in[33], b4, 32, 128);
        k_spmv<16><<<g8, bs8, 0, stream>>>(H0, nullptr, T1_1, row_ptr, edges, N, 1.f);
        k_spmv<16><<<g8, bs8, 0, stream>>>(T1_1, H0, T1_2, row_ptr, edges, N, 2.f);
        TP tp; tp.p[0] = H0; tp.p[1] = T1_1; tp.p[2] = T1_2;
        k_chebgate<u16, 16, 3><<<gv, 256, 0, stream>>>(tp, Wp, b4, L2T[0], N, 32, 128);
    }
    // ---- layer 2: MFMA, K=4, Fin=32, F=64, FPAD=64, one 64-f tile ----
    {
        k_pack_wt<<<(3 * 64 * 128 + 255) / 256, 256, 0, stream>>>(
            (const float*)d_in[34], (const float*)d_in[42], (const float*)d_in[46], Wt, 128, 32, 64, 64);
        k_pack_b3<<<1, 256, 0, stream>>>(
            (const float*)d_in[35], (const float*)d_in[36], (const float*)d_in[37],
            (const float*)d_in[43], (const float*)d_in[44], (const float*)d_in[45],
            (const float*)d_in[47], (const float*)d_in[48], (const float*)d_in[49], b3, 64, 64);
        k_spmv<32><<<g16, bs16, 0, stream>>>(L2T[0], nullptr, L2T[1], row_ptr, edges, N, 1.f);
        k_spmv<32><<<g16, bs16, 0, stream>>>(L2T[1], L2T[0], L2T[2], row_ptr, edges, N, 2.f);
        k_spmv<32><<<g16, bs16, 0, stream>>>(L2T[2], L2T[1], L2T[3], row_ptr, edges, N, 2.f);
        TP tp; for (int t = 0; t < 4; t++) tp.p[t] = L2T[t];
        k_chebgate_mfma<32, 4, 64><<<dim3(rb, 1), 256, 0, stream>>>(tp, Wt, b3, L3T[0], N, 64, 64);
    }
    // ---- layer 3: MFMA, K=5, Fin=64, F=152, FPAD=192, three 64-f tiles ----
    {
        k_pack_wt<<<(3 * 192 * 320 + 255) / 256, 256, 0, stream>>>(
            (const float*)d_in[50], (const float*)d_in[58], (const float*)d_in[62], Wt, 320, 64, 152, 192);
        k_pack_b3<<<3, 256, 0, stream>>>(
            (const float*)d_in[51], (const float*)d_in[52], (const float*)d_in[53],
            (const float*)d_in[59], (const float*)d_in[60], (const float*)d_in[61],
            (const float*)d_in[63], (const float*)d_in[64], (const float*)d_in[65], b3, 152, 192);
        k_spmv<64><<<g32, bs32, 0, stream>>>(L3T[0], nullptr, L3T[1], row_ptr, edges, N, 1.f);
        k_spmv<64><<<g32, bs32, 0, stream>>>(L3T[1], L3T[0], L3T[2], row_ptr, edges, N, 2.f);
        k_spmv<64><<<g32, bs32, 0, stream>>>(L3T[2], L3T[1], L3T[3], row_ptr, edges, N, 2.f);
        k_spmv<64><<<g32, bs32, 0, stream>>>(L3T[3], L3T[2], L3T[4], row_ptr, edges, N, 2.f);
        TP tp; for (int t = 0; t < 5; t++) tp.p[t] = L3T[t];
        k_chebgate_mfma<64, 5, 192><<<dim3(rb, 3), 256, 0, stream>>>(tp, Wt, b3, Hfin, N, 152, 152);
    }

    k_final<<<(N * 64 + 255) / 256, 256, 0, stream>>>(Hfin, (const float*)d_in[66],
                                                      (const float*)d_in[67], (float*)d_out, N);
}

// Round 12
// 1445.697 us; speedup vs baseline: 1.0032x; 1.0032x over previous
//
#include <hip/hip_runtime.h>

// GConvLSTM single step x4 layers, H=C=0 => f-gate dead, peepholes dead.
// bf16 storage; SpMV = R5/R10 best build (8B Edge{src,w}, unroll x4, no NT).
// Chebgate = R10 best (no-LDS, 32-f tiles). NEW in R12:
//  - L3 chebgate fuses the 152->2 final projection into its epilogue
//    (shfl_xor ln-reduction -> per-tile logit partials; no Hfin write),
//  - k_smax sums 5 partials + bias + softmax (replaces k_final),
//  - k_scan writes the fill cursor directly (k_copy dropped).

#define IN_CH 10
typedef unsigned short u16;
typedef unsigned long long u64;
typedef short bf16x8 __attribute__((ext_vector_type(8)));
typedef float f32x4 __attribute__((ext_vector_type(4)));

struct __align__(8) Edge { int s; float w; };

__device__ __forceinline__ float bf2f(u16 u) { return __uint_as_float(((unsigned)u) << 16); }
__device__ __forceinline__ float lo16f(unsigned v) { return __uint_as_float(v << 16); }
__device__ __forceinline__ float hi16f(unsigned v) { return __uint_as_float(v & 0xffff0000u); }
__device__ __forceinline__ u16 f2bf(float f) {
    unsigned x = __float_as_uint(f);
    return (u16)((x + 0x7fff + ((x >> 16) & 1)) >> 16);  // RNE
}
__device__ __forceinline__ float ldv(const float* p) { return *p; }
__device__ __forceinline__ float ldv(const u16* p) { return bf2f(*p); }
__device__ __forceinline__ void stv(float* p, float v) { *p = v; }
__device__ __forceinline__ void stv(u16* p, float v) { *p = f2bf(v); }

// ---------------- graph preprocessing ----------------

__global__ void k_count(const int* __restrict__ dst, int* __restrict__ cnt, int e) {
    int i = blockIdx.x * 256 + threadIdx.x;
    if (i < e) atomicAdd(&cnt[dst[i]], 1);
}

__global__ void k_dinv(const int* __restrict__ cnt, float* __restrict__ dinv, int n) {
    int i = blockIdx.x * 256 + threadIdx.x;
    if (i < n) dinv[i] = cnt[i] > 0 ? rsqrtf((float)cnt[i]) : 0.f;
}

__global__ __launch_bounds__(1024) void k_scan(const int* __restrict__ cnt,
                                               int* __restrict__ row_ptr,
                                               int* __restrict__ cursor, int n) {
    __shared__ int sums[1024];
    int t = threadIdx.x;
    int chunk = (n + 1023) >> 10;
    int lo = t * chunk;
    int hi = lo + chunk < n ? lo + chunk : n;
    int s = 0;
    for (int i = lo; i < hi; i++) s += cnt[i];
    sums[t] = s;
    __syncthreads();
    for (int off = 1; off < 1024; off <<= 1) {
        int v = (t >= off) ? sums[t - off] : 0;
        __syncthreads();
        sums[t] += v;
        __syncthreads();
    }
    int prefix = (t == 0) ? 0 : sums[t - 1];
    for (int i = lo; i < hi; i++) {
        row_ptr[i] = prefix;
        cursor[i] = prefix;
        prefix += cnt[i];
    }
    if (t == 0) row_ptr[n] = sums[1023];
}

__global__ void k_fill(const int* __restrict__ src, const int* __restrict__ dst,
                       const float* __restrict__ dinv, int* __restrict__ cursor,
                       Edge* __restrict__ ed, int e) {
    int i = blockIdx.x * 256 + threadIdx.x;
    if (i >= e) return;
    int s = src[i], d = dst[i];
    int pos = atomicAdd(&cursor[d], 1);
    float w = dinv[s] * dinv[d];
    u64 v = (u64)(unsigned)s | ((u64)__float_as_uint(w) << 32);
    *(u64*)&ed[pos] = v;  // single 8B store
}

// ---------------- Cheb SpMV: full row, unroll x4 ----------------

template <int F>
__global__ void k_spmv(const u16* __restrict__ X, const u16* __restrict__ Tprev,
                       u16* __restrict__ Tout, const int* __restrict__ row_ptr,
                       const Edge* __restrict__ ed, int n, float scale) {
    int lane = threadIdx.x;  // [0, F/2)
    int node = blockIdx.x * blockDim.y + threadIdx.y;
    if (node >= n) return;
    int lo = row_ptr[node], hi = row_ptr[node + 1];
    const u16* Xc = X + 2 * lane;
    float a0 = 0.f, a1 = 0.f, b0 = 0.f, b1 = 0.f;
    float c0 = 0.f, c1 = 0.f, d0 = 0.f, d1 = 0.f;
    int e = lo;
    for (; e + 4 <= hi; e += 4) {
        Edge e0 = ed[e], e1 = ed[e + 1], e2 = ed[e + 2], e3 = ed[e + 3];
        unsigned v0 = *(const unsigned*)(Xc + (size_t)e0.s * F);
        unsigned v1 = *(const unsigned*)(Xc + (size_t)e1.s * F);
        unsigned v2 = *(const unsigned*)(Xc + (size_t)e2.s * F);
        unsigned v3 = *(const unsigned*)(Xc + (size_t)e3.s * F);
        a0 = fmaf(e0.w, lo16f(v0), a0); a1 = fmaf(e0.w, hi16f(v0), a1);
        b0 = fmaf(e1.w, lo16f(v1), b0); b1 = fmaf(e1.w, hi16f(v1), b1);
        c0 = fmaf(e2.w, lo16f(v2), c0); c1 = fmaf(e2.w, hi16f(v2), c1);
        d0 = fmaf(e3.w, lo16f(v3), d0); d1 = fmaf(e3.w, hi16f(v3), d1);
    }
    for (; e < hi; e++) {
        Edge e0 = ed[e];
        unsigned v0 = *(const unsigned*)(Xc + (size_t)e0.s * F);
        a0 = fmaf(e0.w, lo16f(v0), a0); a1 = fmaf(e0.w, hi16f(v0), a1);
    }
    float v0 = -scale * ((a0 + b0) + (c0 + d0));
    float v1 = -scale * ((a1 + b1) + (c1 + d1));
    if (Tprev) {
        unsigned pv = *(const unsigned*)(Tprev + (size_t)node * F + 2 * lane);
        v0 -= lo16f(pv);
        v1 -= hi16f(pv);
    }
    *(unsigned*)(Tout + (size_t)node * F + 2 * lane) =
        (unsigned)f2bf(v0) | ((unsigned)f2bf(v1) << 16);
}

// ---------------- VALU chebgate (layers 0,1) ----------------
struct TP { const void* p[5]; };

template <typename ST, int FIN, int K>
__global__ __launch_bounds__(256) void k_chebgate(TP tp, const float* __restrict__ Wp,
                                                  const float* __restrict__ b4,
                                                  ST* __restrict__ H, int n, int F,
                                                  int F4pad) {
    __shared__ float As[FIN][68];
    __shared__ float Ws[FIN][128];
    const int tid = threadIdx.x;
    const int fx = tid & 31, ry = tid >> 5;
    const int row0 = blockIdx.y * 64;
    const int f0 = blockIdx.x * 32;
    const int f = f0 + fx;

    float acc[8][3];
    const float4 bv = *(const float4*)&b4[(size_t)f * 4];
#pragma unroll
    for (int r = 0; r < 8; r++) { acc[r][0] = bv.x; acc[r][1] = bv.y; acc[r][2] = bv.z; }

#pragma unroll
    for (int t = 0; t < K; t++) {
        const ST* T = (const ST*)tp.p[t];
        for (int idx = tid; idx < 64 * FIN; idx += 256) {
            int r = idx / FIN, a = idx - r * FIN;
            int rr = row0 + r;
            if (rr >= n) rr = n - 1;
            As[a][r] = ldv(&T[(size_t)rr * FIN + a]);
        }
        const float* Wt = Wp + (size_t)t * FIN * F4pad + (size_t)f0 * 4;
        for (int idx = tid; idx < FIN * 128; idx += 256) {
            int aa = idx >> 7, c = idx & 127;
            Ws[aa][c] = Wt[(size_t)aa * F4pad + c];
        }
        __syncthreads();
#pragma unroll 2
        for (int a = 0; a < FIN; a++) {
            const float4 w = *(const float4*)&Ws[a][fx * 4];
            const float4 x0 = *(const float4*)&As[a][ry * 8];
            const float4 x1 = *(const float4*)&As[a][ry * 8 + 4];
            const float xr[8] = {x0.x, x0.y, x0.z, x0.w, x1.x, x1.y, x1.z, x1.w};
#pragma unroll
            for (int r = 0; r < 8; r++) {
                acc[r][0] = fmaf(xr[r], w.x, acc[r][0]);
                acc[r][1] = fmaf(xr[r], w.y, acc[r][1]);
                acc[r][2] = fmaf(xr[r], w.z, acc[r][2]);
            }
        }
        __syncthreads();
    }

    if (f < F) {
#pragma unroll
        for (int r = 0; r < 8; r++) {
            int row = row0 + ry * 8 + r;
            if (row < n) {
                float gi = 1.f / (1.f + __expf(-acc[r][0]));
                float go = 1.f / (1.f + __expf(-acc[r][2]));
                float c = gi * tanhf(acc[r][1]);
                float h = go * tanhf(c);
                stv(&H[(size_t)row * F + f], fmaxf(h, 0.f));
            }
        }
    }
}

// ---------------- MFMA chebgate (layer 2; R10 best: no LDS, 32-f tiles) ----------------

template <int FIN, int K, int FPAD>
__global__ __launch_bounds__(256) void k_chebgate_mfma(TP tp, const u16* __restrict__ Wt,
                                                       const float* __restrict__ b3,
                                                       u16* __restrict__ H, int n, int F,
                                                       int Hstride) {
    constexpr int KT = K * FIN;
    const int wave = threadIdx.x >> 6;
    const int lane = threadIdx.x & 63;
    const int r0 = blockIdx.x * 128 + wave * 32;
    const int f0 = blockIdx.y * 32;
    const int ln = lane & 15;
    const int lk = lane >> 4;

    f32x4 acc[2][2][3];
#pragma unroll
    for (int rt = 0; rt < 2; rt++)
#pragma unroll
        for (int s = 0; s < 2; s++)
#pragma unroll
            for (int g = 0; g < 3; g++) acc[rt][s][g] = (f32x4){0.f, 0.f, 0.f, 0.f};

    int arow[2];
#pragma unroll
    for (int rt = 0; rt < 2; rt++) {
        int row = r0 + rt * 16 + ln;
        arow[rt] = row < n ? row : n - 1;
    }

    for (int k0 = 0; k0 < KT; k0 += 32) {
        const int t = k0 / FIN;
        const int a0 = k0 % FIN;
        const u16* T = (const u16*)tp.p[t];
        bf16x8 af[2];
#pragma unroll
        for (int rt = 0; rt < 2; rt++)
            af[rt] = *(const bf16x8*)(T + (size_t)arow[rt] * FIN + a0 + lk * 8);
#pragma unroll
        for (int s = 0; s < 2; s++) {
#pragma unroll
            for (int g = 0; g < 3; g++) {
                int col = g * FPAD + f0 + s * 16 + ln;
                bf16x8 bf = *(const bf16x8*)(Wt + (size_t)col * KT + k0 + lk * 8);
#pragma unroll
                for (int rt = 0; rt < 2; rt++)
                    acc[rt][s][g] = __builtin_amdgcn_mfma_f32_16x16x32_bf16(
                        af[rt], bf, acc[rt][s][g], 0, 0, 0);
            }
        }
    }

#pragma unroll
    for (int s = 0; s < 2; s++) {
        int fcol = f0 + s * 16 + ln;
        if (fcol >= F) continue;
        float bi = b3[0 * FPAD + fcol];
        float bc = b3[1 * FPAD + fcol];
        float bo = b3[2 * FPAD + fcol];
#pragma unroll
        for (int rt = 0; rt < 2; rt++) {
#pragma unroll
            for (int reg = 0; reg < 4; reg++) {
                int row = r0 + rt * 16 + lk * 4 + reg;
                if (row < n) {
                    float gi = 1.f / (1.f + __expf(-(acc[rt][s][0][reg] + bi)));
                    float go = 1.f / (1.f + __expf(-(acc[rt][s][2][reg] + bo)));
                    float c = gi * tanhf(acc[rt][s][1][reg] + bc);
                    float h = go * tanhf(c);
                    H[(size_t)row * Hstride + fcol] = f2bf(fmaxf(h, 0.f));
                }
            }
        }
    }
}

// ---------------- MFMA chebgate + fused final projection (layer 3) ----------------
// Same GEMM core; epilogue computes h then the 152->2 projection partials:
// 16 ln-lanes hold 16 consecutive fcols of the SAME row (C/D layout) ->
// shfl_xor(1,2,4,8) reduces over ln; ln==0 writes part[tile][row][2].
// Pad fcols (>=F) have zeroed Wt/b3 -> h=0, and W2 guarded to 0.

template <int FIN, int K, int FPAD>
__global__ __launch_bounds__(256) void k_chebgate_mfma_fused(
    TP tp, const u16* __restrict__ Wt, const float* __restrict__ b3,
    const float* __restrict__ W2, float* __restrict__ part, int n, int F) {
    constexpr int KT = K * FIN;
    const int wave = threadIdx.x >> 6;
    const int lane = threadIdx.x & 63;
    const int r0 = blockIdx.x * 128 + wave * 32;
    const int f0 = blockIdx.y * 32;
    const int ln = lane & 15;
    const int lk = lane >> 4;

    f32x4 acc[2][2][3];
#pragma unroll
    for (int rt = 0; rt < 2; rt++)
#pragma unroll
        for (int s = 0; s < 2; s++)
#pragma unroll
            for (int g = 0; g < 3; g++) acc[rt][s][g] = (f32x4){0.f, 0.f, 0.f, 0.f};

    int arow[2];
#pragma unroll
    for (int rt = 0; rt < 2; rt++) {
        int row = r0 + rt * 16 + ln;
        arow[rt] = row < n ? row : n - 1;
    }

    for (int k0 = 0; k0 < KT; k0 += 32) {
        const int t = k0 / FIN;
        const int a0 = k0 % FIN;
        const u16* T = (const u16*)tp.p[t];
        bf16x8 af[2];
#pragma unroll
        for (int rt = 0; rt < 2; rt++)
            af[rt] = *(const bf16x8*)(T + (size_t)arow[rt] * FIN + a0 + lk * 8);
#pragma unroll
        for (int s = 0; s < 2; s++) {
#pragma unroll
            for (int g = 0; g < 3; g++) {
                int col = g * FPAD + f0 + s * 16 + ln;
                bf16x8 bf = *(const bf16x8*)(Wt + (size_t)col * KT + k0 + lk * 8);
#pragma unroll
                for (int rt = 0; rt < 2; rt++)
                    acc[rt][s][g] = __builtin_amdgcn_mfma_f32_16x16x32_bf16(
                        af[rt], bf, acc[rt][s][g], 0, 0, 0);
            }
        }
    }

    float p0[2][4], p1[2][4];
#pragma unroll
    for (int rt = 0; rt < 2; rt++)
#pragma unroll
        for (int reg = 0; reg < 4; reg++) { p0[rt][reg] = 0.f; p1[rt][reg] = 0.f; }

#pragma unroll
    for (int s = 0; s < 2; s++) {
        int fcol = f0 + s * 16 + ln;
        float w20 = fcol < F ? W2[fcol * 2 + 0] : 0.f;
        float w21 = fcol < F ? W2[fcol * 2 + 1] : 0.f;
        float bi = b3[0 * FPAD + fcol];
        float bc = b3[1 * FPAD + fcol];
        float bo = b3[2 * FPAD + fcol];
#pragma unroll
        for (int rt = 0; rt < 2; rt++) {
#pragma unroll
            for (int reg = 0; reg < 4; reg++) {
                float gi = 1.f / (1.f + __expf(-(acc[rt][s][0][reg] + bi)));
                float go = 1.f / (1.f + __expf(-(acc[rt][s][2][reg] + bo)));
                float c = gi * tanhf(acc[rt][s][1][reg] + bc);
                float h = fmaxf(go * tanhf(c), 0.f);
                p0[rt][reg] = fmaf(h, w20, p0[rt][reg]);
                p1[rt][reg] = fmaf(h, w21, p1[rt][reg]);
            }
        }
    }

    // reduce over ln (16 lanes; xor of bits 0..3 stays in-group)
#pragma unroll
    for (int rt = 0; rt < 2; rt++) {
#pragma unroll
        for (int reg = 0; reg < 4; reg++) {
            float v0 = p0[rt][reg], v1 = p1[rt][reg];
#pragma unroll
            for (int m = 1; m <= 8; m <<= 1) {
                v0 += __shfl_xor(v0, m);
                v1 += __shfl_xor(v1, m);
            }
            p0[rt][reg] = v0;
            p1[rt][reg] = v1;
        }
    }

    if (ln == 0) {
        const int tile = blockIdx.y;
#pragma unroll
        for (int rt = 0; rt < 2; rt++) {
#pragma unroll
            for (int reg = 0; reg < 4; reg++) {
                int row = r0 + rt * 16 + lk * 4 + reg;
                if (row < n) {
                    float* pp = part + ((size_t)tile * n + row) * 2;
                    pp[0] = p0[rt][reg];
                    pp[1] = p1[rt][reg];
                }
            }
        }
    }
}

// ---------------- partial-sum + softmax ----------------
__global__ void k_smax(const float* __restrict__ part, const float* __restrict__ b,
                       float* __restrict__ out, int n, int ntiles) {
    int i = blockIdx.x * 256 + threadIdx.x;
    if (i >= n) return;
    float l0 = b[0], l1 = b[1];
    for (int t = 0; t < ntiles; t++) {
        const float* pp = part + ((size_t)t * n + i) * 2;
        l0 += pp[0];
        l1 += pp[1];
    }
    float m = fmaxf(l0, l1);
    float e0 = __expf(l0 - m), e1 = __expf(l1 - m);
    float s = 1.f / (e0 + e1);
    out[(size_t)i * 2 + 0] = e0 * s;
    out[(size_t)i * 2 + 1] = e1 * s;
}

// ---------------- weight/bias packing ----------------

__global__ void k_pack_w(const float* __restrict__ Wi, const float* __restrict__ Wc,
                         const float* __restrict__ Wo, float* __restrict__ Wp,
                         int KFIN, int F, int F4pad) {
    int idx = blockIdx.x * 256 + threadIdx.x;
    int tot = KFIN * F4pad;
    if (idx >= tot) return;
    int c = idx % F4pad;
    int ka = idx / F4pad;
    int f = c >> 2, g = c & 3;
    float v = 0.f;
    if (g < 3 && f < F) {
        const float* Wg = (g == 0) ? Wi : ((g == 1) ? Wc : Wo);
        v = Wg[(size_t)ka * F + f];
    }
    Wp[idx] = v;
}

__global__ void k_pack_b(const float* __restrict__ bxi, const float* __restrict__ bhi,
                         const float* __restrict__ bi, const float* __restrict__ bxc,
                         const float* __restrict__ bhc, const float* __restrict__ bc,
                         const float* __restrict__ bxo, const float* __restrict__ bho,
                         const float* __restrict__ bo, float* __restrict__ b4,
                         int F, int F4pad) {
    int idx = blockIdx.x * 256 + threadIdx.x;
    if (idx >= F4pad) return;
    int f = idx >> 2, g = idx & 3;
    float v = 0.f;
    if (g < 3 && f < F) {
        if (g == 0) v = bxi[f] + bhi[f] + bi[f];
        else if (g == 1) v = bxc[f] + bhc[f] + bc[f];
        else v = bxo[f] + bho[f] + bo[f];
    }
    b4[idx] = v;
}

__global__ void k_pack_wt(const float* __restrict__ Wi, const float* __restrict__ Wc,
                          const float* __restrict__ Wo, u16* __restrict__ Wt,
                          int KT, int Fin, int F, int FPAD) {
    int idx = blockIdx.x * 256 + threadIdx.x;
    int tot = 3 * FPAD * KT;
    if (idx >= tot) return;
    int k = idx % KT;
    int col = idx / KT;
    int g = col / FPAD, f = col % FPAD;
    int t = k / Fin, a = k % Fin;
    float v = 0.f;
    if (f < F) {
        const float* Wg = (g == 0) ? Wi : ((g == 1) ? Wc : Wo);
        v = Wg[((size_t)t * Fin + a) * F + f];
    }
    Wt[idx] = f2bf(v);
}

__global__ void k_pack_b3(const float* __restrict__ bxi, const float* __restrict__ bhi,
                          const float* __restrict__ bi, const float* __restrict__ bxc,
                          const float* __restrict__ bhc, const float* __restrict__ bc,
                          const float* __restrict__ bxo, const float* __restrict__ bho,
                          const float* __restrict__ bo, float* __restrict__ b3,
                          int F, int FPAD) {
    int idx = blockIdx.x * 256 + threadIdx.x;
    if (idx >= 3 * FPAD) return;
    int g = idx / FPAD, f = idx % FPAD;
    float v = 0.f;
    if (f < F) {
        if (g == 0) v = bxi[f] + bhi[f] + bi[f];
        else if (g == 1) v = bxc[f] + bhc[f] + bc[f];
        else v = bxo[f] + bho[f] + bo[f];
    }
    b3[idx] = v;
}

__global__ void k_cvt(const float* __restrict__ x, u16* __restrict__ y, int n) {
    int i = blockIdx.x * 256 + threadIdx.x;
    if (i < n) y[i] = f2bf(x[i]);
}

// ---------------- launch ----------------

static inline size_t al(size_t x) { return (x + 255) & ~(size_t)255; }

extern "C" void kernel_launch(void* const* d_in, const int* in_sizes, int n_in,
                              void* d_out, int out_size, void* d_ws, size_t ws_size,
                              hipStream_t stream) {
    const float* X0 = (const float*)d_in[0];
    const int* ei = (const int*)d_in[1];
    const int N = in_sizes[0] / IN_CH;
    const int E = in_sizes[1] / 2;
    const int* src = ei;
    const int* dst = ei + E;

    // ---- workspace carve (~122 MB) ----
    char* p = (char*)d_ws;
    size_t off = 0;
    auto carve = [&](size_t bytes) -> char* { char* r = p + off; off += al(bytes); return r; };
    int* row_ptr  = (int*)carve((size_t)(N + 1) * 4);
    int* cnt      = (int*)carve((size_t)N * 4);   // doubles as cursor
    float* dinv   = (float*)carve((size_t)N * 4);
    Edge* edges   = (Edge*)carve((size_t)E * 8);
    const size_t S64 = al((size_t)N * 64 * 2);
    char* bufA    = carve(5 * S64);               // 64 MB
    char* bufB    = carve((size_t)N * 304);       // 30.4 MB
    float* Wp     = (float*)carve((size_t)48 * 128 * 4);
    float* b4     = (float*)carve((size_t)128 * 4);
    u16* Wt       = (u16*)carve((size_t)480 * 320 * 2);
    float* b3     = (float*)carve((size_t)480 * 4);
    (void)ws_size;

    u16* X0c  = (u16*)bufA;                                   // N x 10
    u16* T0_1 = (u16*)(bufA + al((size_t)N * 20));            // N x 10
    u16* H0   = (u16*)(bufA + S64);                           // N x 16
    u16* T1_1 = (u16*)(bufA + S64 + al((size_t)N * 32));      // N x 16
    u16* T1_2 = (u16*)(bufA + S64 + 2 * al((size_t)N * 32));  // N x 16
    u16* L2T[4];
    for (int t = 0; t < 4; t++) L2T[t] = (u16*)(bufB + t * al((size_t)N * 64));
    u16* L3T[5];
    for (int t = 0; t < 5; t++) L3T[t] = (u16*)(bufA + t * S64);
    float* part = (float*)bufB;                               // 5 x N x 2 fp32 (4 MB)

    // ---- graph preprocessing ----
    int gE = (E + 255) / 256, gN = (N + 255) / 256;
    hipMemsetAsync(cnt, 0, (size_t)N * 4, stream);
    k_count<<<gE, 256, 0, stream>>>(dst, cnt, E);
    k_dinv<<<gN, 256, 0, stream>>>(cnt, dinv, N);
    k_scan<<<1, 1024, 0, stream>>>(cnt, row_ptr, cnt, N);  // cnt becomes cursor
    k_fill<<<gE, 256, 0, stream>>>(src, dst, dinv, cnt, edges, E);

    k_cvt<<<(N * IN_CH + 255) / 256, 256, 0, stream>>>(X0, X0c, N * IN_CH);

    dim3 gv(1, (N + 63) / 64);
    int rb = (N + 127) / 128;

    // spmv shapes: LPN = F/2 lanes per node
    dim3 bs5(5, 48);   int g5 = (N + 47) / 48;
    dim3 bs8(8, 32);   int g8 = (N + 31) / 32;
    dim3 bs16(16, 16); int g16 = (N + 15) / 16;
    dim3 bs32(32, 8);  int g32 = (N + 7) / 8;

    // ---- layer 0: VALU, K=2, Fin=10, F=16 ----
    {
        k_pack_w<<<(20 * 128 + 255) / 256, 256, 0, stream>>>(
            (const float*)d_in[2], (const float*)d_in[10], (const float*)d_in[14], Wp, 20, 16, 128);
        k_pack_b<<<1, 256, 0, stream>>>(
            (const float*)d_in[3], (const float*)d_in[4], (const float*)d_in[5],
            (const float*)d_in[11], (const float*)d_in[12], (const float*)d_in[13],
            (const float*)d_in[15], (const float*)d_in[16], (const float*)d_in[17], b4, 16, 128);
        k_spmv<10><<<g5, bs5, 0, stream>>>(X0c, nullptr, T0_1, row_ptr, edges, N, 1.f);
        TP tp; tp.p[0] = X0c; tp.p[1] = T0_1;
        k_chebgate<u16, 10, 2><<<gv, 256, 0, stream>>>(tp, Wp, b4, H0, N, 16, 128);
    }
    // ---- layer 1: VALU, K=3, Fin=16, F=32 ----
    {
        k_pack_w<<<(48 * 128 + 255) / 256, 256, 0, stream>>>(
            (const float*)d_in[18], (const float*)d_in[26], (const float*)d_in[30], Wp, 48, 32, 128);
        k_pack_b<<<1, 256, 0, stream>>>(
            (const float*)d_in[19], (const float*)d_in[20], (const float*)d_in[21],
            (const float*)d_in[27], (const float*)d_in[28], (const float*)d_in[29],
            (const float*)d_in[31], (const float*)d_in[32], (const float*)d_in[33], b4, 32, 128);
        k_spmv<16><<<g8, bs8, 0, stream>>>(H0, nullptr, T1_1, row_ptr, edges, N, 1.f);
        k_spmv<16><<<g8, bs8, 0, stream>>>(T1_1, H0, T1_2, row_ptr, edges, N, 2.f);
        TP tp; tp.p[0] = H0; tp.p[1] = T1_1; tp.p[2] = T1_2;
        k_chebgate<u16, 16, 3><<<gv, 256, 0, stream>>>(tp, Wp, b4, L2T[0], N, 32, 128);
    }
    // ---- layer 2: MFMA, K=4, Fin=32, F=64 ----
    {
        k_pack_wt<<<(3 * 64 * 128 + 255) / 256, 256, 0, stream>>>(
            (const float*)d_in[34], (const float*)d_in[42], (const float*)d_in[46], Wt, 128, 32, 64, 64);
        k_pack_b3<<<1, 256, 0, stream>>>(
            (const float*)d_in[35], (const float*)d_in[36], (const float*)d_in[37],
            (const float*)d_in[43], (const float*)d_in[44], (const float*)d_in[45],
            (const float*)d_in[47], (const float*)d_in[48], (const float*)d_in[49], b3, 64, 64);
        k_spmv<32><<<g16, bs16, 0, stream>>>(L2T[0], nullptr, L2T[1], row_ptr, edges, N, 1.f);
        k_spmv<32><<<g16, bs16, 0, stream>>>(L2T[1], L2T[0], L2T[2], row_ptr, edges, N, 2.f);
        k_spmv<32><<<g16, bs16, 0, stream>>>(L2T[2], L2T[1], L2T[3], row_ptr, edges, N, 2.f);
        TP tp; for (int t = 0; t < 4; t++) tp.p[t] = L2T[t];
        k_chebgate_mfma<32, 4, 64><<<dim3(rb, 2), 256, 0, stream>>>(tp, Wt, b3, L3T[0], N, 64, 64);
    }
    // ---- layer 3: MFMA + fused final projection, K=5, Fin=64, F=152 ----
    {
        k_pack_wt<<<(3 * 160 * 320 + 255) / 256, 256, 0, stream>>>(
            (const float*)d_in[50], (const float*)d_in[58], (const float*)d_in[62], Wt, 320, 64, 152, 160);
        k_pack_b3<<<2, 256, 0, stream>>>(
            (const float*)d_in[51], (const float*)d_in[52], (const float*)d_in[53],
            (const float*)d_in[59], (const float*)d_in[60], (const float*)d_in[61],
            (const float*)d_in[63], (const float*)d_in[64], (const float*)d_in[65], b3, 152, 160);
        k_spmv<64><<<g32, bs32, 0, stream>>>(L3T[0], nullptr, L3T[1], row_ptr, edges, N, 1.f);
        k_spmv<64><<<g32, bs32, 0, stream>>>(L3T[1], L3T[0], L3T[2], row_ptr, edges, N, 2.f);
        k_spmv<64><<<g32, bs32, 0, stream>>>(L3T[2], L3T[1], L3T[3], row_ptr, edges, N, 2.f);
        k_spmv<64><<<g32, bs32, 0, stream>>>(L3T[3], L3T[2], L3T[4], row_ptr, edges, N, 2.f);
        TP tp; for (int t = 0; t < 5; t++) tp.p[t] = L3T[t];
        k_chebgate_mfma_fused<64, 5, 160><<<dim3(rb, 5), 256, 0, stream>>>(
            tp, Wt, b3, (const float*)d_in[66], part, N, 152);
    }

    k_smax<<<gN, 256, 0, stream>>>(part, (const float*)d_in[67], (float*)d_out, N, 5);
}

// Round 13
// 1266.454 us; speedup vs baseline: 1.1452x; 1.1415x over previous
//
#include <hip/hip_runtime.h>

// GConvLSTM single step x4 layers, H=C=0 => f-gate dead, peepholes dead.
// bf16 storage; SpMV = R5/R10 best (8B Edge{src,w}, unroll x4, no NT).
// Chebgate = R10 best (no-LDS, 32-f tiles); L3 fuses 152->2 projection (R12).
// NEW R13: parallel 3-kernel prefix scan (k_bsum/k_bscan/k_write) replaces the
// single-block k_scan (R12 counters: 228us at 0.07% occupancy — serial CU).

#define IN_CH 10
typedef unsigned short u16;
typedef unsigned long long u64;
typedef short bf16x8 __attribute__((ext_vector_type(8)));
typedef float f32x4 __attribute__((ext_vector_type(4)));

struct __align__(8) Edge { int s; float w; };

__device__ __forceinline__ float bf2f(u16 u) { return __uint_as_float(((unsigned)u) << 16); }
__device__ __forceinline__ float lo16f(unsigned v) { return __uint_as_float(v << 16); }
__device__ __forceinline__ float hi16f(unsigned v) { return __uint_as_float(v & 0xffff0000u); }
__device__ __forceinline__ u16 f2bf(float f) {
    unsigned x = __float_as_uint(f);
    return (u16)((x + 0x7fff + ((x >> 16) & 1)) >> 16);  // RNE
}
__device__ __forceinline__ float ldv(const float* p) { return *p; }
__device__ __forceinline__ float ldv(const u16* p) { return bf2f(*p); }
__device__ __forceinline__ void stv(float* p, float v) { *p = v; }
__device__ __forceinline__ void stv(u16* p, float v) { *p = f2bf(v); }

// ---------------- graph preprocessing ----------------

__global__ void k_count(const int* __restrict__ dst, int* __restrict__ cnt, int e) {
    int i = blockIdx.x * 256 + threadIdx.x;
    if (i < e) atomicAdd(&cnt[dst[i]], 1);
}

__global__ void k_dinv(const int* __restrict__ cnt, float* __restrict__ dinv, int n) {
    int i = blockIdx.x * 256 + threadIdx.x;
    if (i < n) dinv[i] = cnt[i] > 0 ? rsqrtf((float)cnt[i]) : 0.f;
}

// ---- parallel scan: 1024 elems per 256-thread block ----

__global__ void k_bsum(const int* __restrict__ cnt, int* __restrict__ bsum, int n) {
    __shared__ int red[256];
    int t = threadIdx.x;
    int idx = blockIdx.x * 1024 + t * 4;
    int s = 0;
#pragma unroll
    for (int j = 0; j < 4; j++) s += (idx + j < n) ? cnt[idx + j] : 0;
    red[t] = s;
    __syncthreads();
    for (int off = 128; off > 0; off >>= 1) {
        if (t < off) red[t] += red[t + off];
        __syncthreads();
    }
    if (t == 0) bsum[blockIdx.x] = red[0];
}

__global__ __launch_bounds__(1024) void k_bscan(const int* __restrict__ bsum,
                                                int* __restrict__ boff,
                                                int* __restrict__ total_out, int B) {
    __shared__ int sh[1024];
    int t = threadIdx.x;
    int v = t < B ? bsum[t] : 0;
    sh[t] = v;
    __syncthreads();
    for (int off = 1; off < 1024; off <<= 1) {
        int x = (t >= off) ? sh[t - off] : 0;
        __syncthreads();
        sh[t] += x;
        __syncthreads();
    }
    if (t < B) boff[t] = sh[t] - v;  // exclusive
    if (t == B - 1) *total_out = sh[t];
}

__global__ void k_write(const int* __restrict__ cnt, const int* __restrict__ boff,
                        int* __restrict__ row_ptr, int* __restrict__ cursor, int n) {
    __shared__ int tsum[256];
    int t = threadIdx.x;
    int idx = blockIdx.x * 1024 + t * 4;
    int c[4];
    int s = 0;
#pragma unroll
    for (int j = 0; j < 4; j++) {
        c[j] = (idx + j < n) ? cnt[idx + j] : 0;
        s += c[j];
    }
    tsum[t] = s;
    __syncthreads();
    for (int off = 1; off < 256; off <<= 1) {
        int x = (t >= off) ? tsum[t - off] : 0;
        __syncthreads();
        tsum[t] += x;
        __syncthreads();
    }
    int run = boff[blockIdx.x] + tsum[t] - s;  // exclusive prefix for this thread
#pragma unroll
    for (int j = 0; j < 4; j++) {
        if (idx + j < n) {
            row_ptr[idx + j] = run;
            cursor[idx + j] = run;
            run += c[j];
        }
    }
}

__global__ void k_fill(const int* __restrict__ src, const int* __restrict__ dst,
                       const float* __restrict__ dinv, int* __restrict__ cursor,
                       Edge* __restrict__ ed, int e) {
    int i = blockIdx.x * 256 + threadIdx.x;
    if (i >= e) return;
    int s = src[i], d = dst[i];
    int pos = atomicAdd(&cursor[d], 1);
    float w = dinv[s] * dinv[d];
    u64 v = (u64)(unsigned)s | ((u64)__float_as_uint(w) << 32);
    *(u64*)&ed[pos] = v;  // single 8B store
}

// ---------------- Cheb SpMV: full row, unroll x4 ----------------

template <int F>
__global__ void k_spmv(const u16* __restrict__ X, const u16* __restrict__ Tprev,
                       u16* __restrict__ Tout, const int* __restrict__ row_ptr,
                       const Edge* __restrict__ ed, int n, float scale) {
    int lane = threadIdx.x;  // [0, F/2)
    int node = blockIdx.x * blockDim.y + threadIdx.y;
    if (node >= n) return;
    int lo = row_ptr[node], hi = row_ptr[node + 1];
    const u16* Xc = X + 2 * lane;
    float a0 = 0.f, a1 = 0.f, b0 = 0.f, b1 = 0.f;
    float c0 = 0.f, c1 = 0.f, d0 = 0.f, d1 = 0.f;
    int e = lo;
    for (; e + 4 <= hi; e += 4) {
        Edge e0 = ed[e], e1 = ed[e + 1], e2 = ed[e + 2], e3 = ed[e + 3];
        unsigned v0 = *(const unsigned*)(Xc + (size_t)e0.s * F);
        unsigned v1 = *(const unsigned*)(Xc + (size_t)e1.s * F);
        unsigned v2 = *(const unsigned*)(Xc + (size_t)e2.s * F);
        unsigned v3 = *(const unsigned*)(Xc + (size_t)e3.s * F);
        a0 = fmaf(e0.w, lo16f(v0), a0); a1 = fmaf(e0.w, hi16f(v0), a1);
        b0 = fmaf(e1.w, lo16f(v1), b0); b1 = fmaf(e1.w, hi16f(v1), b1);
        c0 = fmaf(e2.w, lo16f(v2), c0); c1 = fmaf(e2.w, hi16f(v2), c1);
        d0 = fmaf(e3.w, lo16f(v3), d0); d1 = fmaf(e3.w, hi16f(v3), d1);
    }
    for (; e < hi; e++) {
        Edge e0 = ed[e];
        unsigned v0 = *(const unsigned*)(Xc + (size_t)e0.s * F);
        a0 = fmaf(e0.w, lo16f(v0), a0); a1 = fmaf(e0.w, hi16f(v0), a1);
    }
    float v0 = -scale * ((a0 + b0) + (c0 + d0));
    float v1 = -scale * ((a1 + b1) + (c1 + d1));
    if (Tprev) {
        unsigned pv = *(const unsigned*)(Tprev + (size_t)node * F + 2 * lane);
        v0 -= lo16f(pv);
        v1 -= hi16f(pv);
    }
    *(unsigned*)(Tout + (size_t)node * F + 2 * lane) =
        (unsigned)f2bf(v0) | ((unsigned)f2bf(v1) << 16);
}

// ---------------- VALU chebgate (layers 0,1) ----------------
struct TP { const void* p[5]; };

template <typename ST, int FIN, int K>
__global__ __launch_bounds__(256) void k_chebgate(TP tp, const float* __restrict__ Wp,
                                                  const float* __restrict__ b4,
                                                  ST* __restrict__ H, int n, int F,
                                                  int F4pad) {
    __shared__ float As[FIN][68];
    __shared__ float Ws[FIN][128];
    const int tid = threadIdx.x;
    const int fx = tid & 31, ry = tid >> 5;
    const int row0 = blockIdx.y * 64;
    const int f0 = blockIdx.x * 32;
    const int f = f0 + fx;

    float acc[8][3];
    const float4 bv = *(const float4*)&b4[(size_t)f * 4];
#pragma unroll
    for (int r = 0; r < 8; r++) { acc[r][0] = bv.x; acc[r][1] = bv.y; acc[r][2] = bv.z; }

#pragma unroll
    for (int t = 0; t < K; t++) {
        const ST* T = (const ST*)tp.p[t];
        for (int idx = tid; idx < 64 * FIN; idx += 256) {
            int r = idx / FIN, a = idx - r * FIN;
            int rr = row0 + r;
            if (rr >= n) rr = n - 1;
            As[a][r] = ldv(&T[(size_t)rr * FIN + a]);
        }
        const float* Wt = Wp + (size_t)t * FIN * F4pad + (size_t)f0 * 4;
        for (int idx = tid; idx < FIN * 128; idx += 256) {
            int aa = idx >> 7, c = idx & 127;
            Ws[aa][c] = Wt[(size_t)aa * F4pad + c];
        }
        __syncthreads();
#pragma unroll 2
        for (int a = 0; a < FIN; a++) {
            const float4 w = *(const float4*)&Ws[a][fx * 4];
            const float4 x0 = *(const float4*)&As[a][ry * 8];
            const float4 x1 = *(const float4*)&As[a][ry * 8 + 4];
            const float xr[8] = {x0.x, x0.y, x0.z, x0.w, x1.x, x1.y, x1.z, x1.w};
#pragma unroll
            for (int r = 0; r < 8; r++) {
                acc[r][0] = fmaf(xr[r], w.x, acc[r][0]);
                acc[r][1] = fmaf(xr[r], w.y, acc[r][1]);
                acc[r][2] = fmaf(xr[r], w.z, acc[r][2]);
            }
        }
        __syncthreads();
    }

    if (f < F) {
#pragma unroll
        for (int r = 0; r < 8; r++) {
            int row = row0 + ry * 8 + r;
            if (row < n) {
                float gi = 1.f / (1.f + __expf(-acc[r][0]));
                float go = 1.f / (1.f + __expf(-acc[r][2]));
                float c = gi * tanhf(acc[r][1]);
                float h = go * tanhf(c);
                stv(&H[(size_t)row * F + f], fmaxf(h, 0.f));
            }
        }
    }
}

// ---------------- MFMA chebgate (layer 2; R10 best: no LDS, 32-f tiles) ----------------

template <int FIN, int K, int FPAD>
__global__ __launch_bounds__(256) void k_chebgate_mfma(TP tp, const u16* __restrict__ Wt,
                                                       const float* __restrict__ b3,
                                                       u16* __restrict__ H, int n, int F,
                                                       int Hstride) {
    constexpr int KT = K * FIN;
    const int wave = threadIdx.x >> 6;
    const int lane = threadIdx.x & 63;
    const int r0 = blockIdx.x * 128 + wave * 32;
    const int f0 = blockIdx.y * 32;
    const int ln = lane & 15;
    const int lk = lane >> 4;

    f32x4 acc[2][2][3];
#pragma unroll
    for (int rt = 0; rt < 2; rt++)
#pragma unroll
        for (int s = 0; s < 2; s++)
#pragma unroll
            for (int g = 0; g < 3; g++) acc[rt][s][g] = (f32x4){0.f, 0.f, 0.f, 0.f};

    int arow[2];
#pragma unroll
    for (int rt = 0; rt < 2; rt++) {
        int row = r0 + rt * 16 + ln;
        arow[rt] = row < n ? row : n - 1;
    }

    for (int k0 = 0; k0 < KT; k0 += 32) {
        const int t = k0 / FIN;
        const int a0 = k0 % FIN;
        const u16* T = (const u16*)tp.p[t];
        bf16x8 af[2];
#pragma unroll
        for (int rt = 0; rt < 2; rt++)
            af[rt] = *(const bf16x8*)(T + (size_t)arow[rt] * FIN + a0 + lk * 8);
#pragma unroll
        for (int s = 0; s < 2; s++) {
#pragma unroll
            for (int g = 0; g < 3; g++) {
                int col = g * FPAD + f0 + s * 16 + ln;
                bf16x8 bf = *(const bf16x8*)(Wt + (size_t)col * KT + k0 + lk * 8);
#pragma unroll
                for (int rt = 0; rt < 2; rt++)
                    acc[rt][s][g] = __builtin_amdgcn_mfma_f32_16x16x32_bf16(
                        af[rt], bf, acc[rt][s][g], 0, 0, 0);
            }
        }
    }

#pragma unroll
    for (int s = 0; s < 2; s++) {
        int fcol = f0 + s * 16 + ln;
        if (fcol >= F) continue;
        float bi = b3[0 * FPAD + fcol];
        float bc = b3[1 * FPAD + fcol];
        float bo = b3[2 * FPAD + fcol];
#pragma unroll
        for (int rt = 0; rt < 2; rt++) {
#pragma unroll
            for (int reg = 0; reg < 4; reg++) {
                int row = r0 + rt * 16 + lk * 4 + reg;
                if (row < n) {
                    float gi = 1.f / (1.f + __expf(-(acc[rt][s][0][reg] + bi)));
                    float go = 1.f / (1.f + __expf(-(acc[rt][s][2][reg] + bo)));
                    float c = gi * tanhf(acc[rt][s][1][reg] + bc);
                    float h = go * tanhf(c);
                    H[(size_t)row * Hstride + fcol] = f2bf(fmaxf(h, 0.f));
                }
            }
        }
    }
}

// ---------------- MFMA chebgate + fused final projection (layer 3) ----------------

template <int FIN, int K, int FPAD>
__global__ __launch_bounds__(256) void k_chebgate_mfma_fused(
    TP tp, const u16* __restrict__ Wt, const float* __restrict__ b3,
    const float* __restrict__ W2, float* __restrict__ part, int n, int F) {
    constexpr int KT = K * FIN;
    const int wave = threadIdx.x >> 6;
    const int lane = threadIdx.x & 63;
    const int r0 = blockIdx.x * 128 + wave * 32;
    const int f0 = blockIdx.y * 32;
    const int ln = lane & 15;
    const int lk = lane >> 4;

    f32x4 acc[2][2][3];
#pragma unroll
    for (int rt = 0; rt < 2; rt++)
#pragma unroll
        for (int s = 0; s < 2; s++)
#pragma unroll
            for (int g = 0; g < 3; g++) acc[rt][s][g] = (f32x4){0.f, 0.f, 0.f, 0.f};

    int arow[2];
#pragma unroll
    for (int rt = 0; rt < 2; rt++) {
        int row = r0 + rt * 16 + ln;
        arow[rt] = row < n ? row : n - 1;
    }

    for (int k0 = 0; k0 < KT; k0 += 32) {
        const int t = k0 / FIN;
        const int a0 = k0 % FIN;
        const u16* T = (const u16*)tp.p[t];
        bf16x8 af[2];
#pragma unroll
        for (int rt = 0; rt < 2; rt++)
            af[rt] = *(const bf16x8*)(T + (size_t)arow[rt] * FIN + a0 + lk * 8);
#pragma unroll
        for (int s = 0; s < 2; s++) {
#pragma unroll
            for (int g = 0; g < 3; g++) {
                int col = g * FPAD + f0 + s * 16 + ln;
                bf16x8 bf = *(const bf16x8*)(Wt + (size_t)col * KT + k0 + lk * 8);
#pragma unroll
                for (int rt = 0; rt < 2; rt++)
                    acc[rt][s][g] = __builtin_amdgcn_mfma_f32_16x16x32_bf16(
                        af[rt], bf, acc[rt][s][g], 0, 0, 0);
            }
        }
    }

    float p0[2][4], p1[2][4];
#pragma unroll
    for (int rt = 0; rt < 2; rt++)
#pragma unroll
        for (int reg = 0; reg < 4; reg++) { p0[rt][reg] = 0.f; p1[rt][reg] = 0.f; }

#pragma unroll
    for (int s = 0; s < 2; s++) {
        int fcol = f0 + s * 16 + ln;
        float w20 = fcol < F ? W2[fcol * 2 + 0] : 0.f;
        float w21 = fcol < F ? W2[fcol * 2 + 1] : 0.f;
        float bi = b3[0 * FPAD + fcol];
        float bc = b3[1 * FPAD + fcol];
        float bo = b3[2 * FPAD + fcol];
#pragma unroll
        for (int rt = 0; rt < 2; rt++) {
#pragma unroll
            for (int reg = 0; reg < 4; reg++) {
                float gi = 1.f / (1.f + __expf(-(acc[rt][s][0][reg] + bi)));
                float go = 1.f / (1.f + __expf(-(acc[rt][s][2][reg] + bo)));
                float c = gi * tanhf(acc[rt][s][1][reg] + bc);
                float h = fmaxf(go * tanhf(c), 0.f);
                p0[rt][reg] = fmaf(h, w20, p0[rt][reg]);
                p1[rt][reg] = fmaf(h, w21, p1[rt][reg]);
            }
        }
    }

#pragma unroll
    for (int rt = 0; rt < 2; rt++) {
#pragma unroll
        for (int reg = 0; reg < 4; reg++) {
            float v0 = p0[rt][reg], v1 = p1[rt][reg];
#pragma unroll
            for (int m = 1; m <= 8; m <<= 1) {
                v0 += __shfl_xor(v0, m);
                v1 += __shfl_xor(v1, m);
            }
            p0[rt][reg] = v0;
            p1[rt][reg] = v1;
        }
    }

    if (ln == 0) {
        const int tile = blockIdx.y;
#pragma unroll
        for (int rt = 0; rt < 2; rt++) {
#pragma unroll
            for (int reg = 0; reg < 4; reg++) {
                int row = r0 + rt * 16 + lk * 4 + reg;
                if (row < n) {
                    float* pp = part + ((size_t)tile * n + row) * 2;
                    pp[0] = p0[rt][reg];
                    pp[1] = p1[rt][reg];
                }
            }
        }
    }
}

// ---------------- partial-sum + softmax ----------------
__global__ void k_smax(const float* __restrict__ part, const float* __restrict__ b,
                       float* __restrict__ out, int n, int ntiles) {
    int i = blockIdx.x * 256 + threadIdx.x;
    if (i >= n) return;
    float l0 = b[0], l1 = b[1];
    for (int t = 0; t < ntiles; t++) {
        const float* pp = part + ((size_t)t * n + i) * 2;
        l0 += pp[0];
        l1 += pp[1];
    }
    float m = fmaxf(l0, l1);
    float e0 = __expf(l0 - m), e1 = __expf(l1 - m);
    float s = 1.f / (e0 + e1);
    out[(size_t)i * 2 + 0] = e0 * s;
    out[(size_t)i * 2 + 1] = e1 * s;
}

// ---------------- weight/bias packing ----------------

__global__ void k_pack_w(const float* __restrict__ Wi, const float* __restrict__ Wc,
                         const float* __restrict__ Wo, float* __restrict__ Wp,
                         int KFIN, int F, int F4pad) {
    int idx = blockIdx.x * 256 + threadIdx.x;
    int tot = KFIN * F4pad;
    if (idx >= tot) return;
    int c = idx % F4pad;
    int ka = idx / F4pad;
    int f = c >> 2, g = c & 3;
    float v = 0.f;
    if (g < 3 && f < F) {
        const float* Wg = (g == 0) ? Wi : ((g == 1) ? Wc : Wo);
        v = Wg[(size_t)ka * F + f];
    }
    Wp[idx] = v;
}

__global__ void k_pack_b(const float* __restrict__ bxi, const float* __restrict__ bhi,
                         const float* __restrict__ bi, const float* __restrict__ bxc,
                         const float* __restrict__ bhc, const float* __restrict__ bc,
                         const float* __restrict__ bxo, const float* __restrict__ bho,
                         const float* __restrict__ bo, float* __restrict__ b4,
                         int F, int F4pad) {
    int idx = blockIdx.x * 256 + threadIdx.x;
    if (idx >= F4pad) return;
    int f = idx >> 2, g = idx & 3;
    float v = 0.f;
    if (g < 3 && f < F) {
        if (g == 0) v = bxi[f] + bhi[f] + bi[f];
        else if (g == 1) v = bxc[f] + bhc[f] + bc[f];
        else v = bxo[f] + bho[f] + bo[f];
    }
    b4[idx] = v;
}

__global__ void k_pack_wt(const float* __restrict__ Wi, const float* __restrict__ Wc,
                          const float* __restrict__ Wo, u16* __restrict__ Wt,
                          int KT, int Fin, int F, int FPAD) {
    int idx = blockIdx.x * 256 + threadIdx.x;
    int tot = 3 * FPAD * KT;
    if (idx >= tot) return;
    int k = idx % KT;
    int col = idx / KT;
    int g = col / FPAD, f = col % FPAD;
    int t = k / Fin, a = k % Fin;
    float v = 0.f;
    if (f < F) {
        const float* Wg = (g == 0) ? Wi : ((g == 1) ? Wc : Wo);
        v = Wg[((size_t)t * Fin + a) * F + f];
    }
    Wt[idx] = f2bf(v);
}

__global__ void k_pack_b3(const float* __restrict__ bxi, const float* __restrict__ bhi,
                          const float* __restrict__ bi, const float* __restrict__ bxc,
                          const float* __restrict__ bhc, const float* __restrict__ bc,
                          const float* __restrict__ bxo, const float* __restrict__ bho,
                          const float* __restrict__ bo, float* __restrict__ b3,
                          int F, int FPAD) {
    int idx = blockIdx.x * 256 + threadIdx.x;
    if (idx >= 3 * FPAD) return;
    int g = idx / FPAD, f = idx % FPAD;
    float v = 0.f;
    if (f < F) {
        if (g == 0) v = bxi[f] + bhi[f] + bi[f];
        else if (g == 1) v = bxc[f] + bhc[f] + bc[f];
        else v = bxo[f] + bho[f] + bo[f];
    }
    b3[idx] = v;
}

__global__ void k_cvt(const float* __restrict__ x, u16* __restrict__ y, int n) {
    int i = blockIdx.x * 256 + threadIdx.x;
    if (i < n) y[i] = f2bf(x[i]);
}

// ---------------- launch ----------------

static inline size_t al(size_t x) { return (x + 255) & ~(size_t)255; }

extern "C" void kernel_launch(void* const* d_in, const int* in_sizes, int n_in,
                              void* d_out, int out_size, void* d_ws, size_t ws_size,
                              hipStream_t stream) {
    const float* X0 = (const float*)d_in[0];
    const int* ei = (const int*)d_in[1];
    const int N = in_sizes[0] / IN_CH;
    const int E = in_sizes[1] / 2;
    const int* src = ei;
    const int* dst = ei + E;

    // ---- workspace carve (~122 MB) ----
    char* p = (char*)d_ws;
    size_t off = 0;
    auto carve = [&](size_t bytes) -> char* { char* r = p + off; off += al(bytes); return r; };
    int* row_ptr  = (int*)carve((size_t)(N + 1) * 4);
    int* cnt      = (int*)carve((size_t)N * 4);
    int* cursor   = (int*)carve((size_t)N * 4);
    float* dinv   = (float*)carve((size_t)N * 4);
    int* bsum     = (int*)carve((size_t)1024 * 4);
    int* boff     = (int*)carve((size_t)1024 * 4);
    Edge* edges   = (Edge*)carve((size_t)E * 8);
    const size_t S64 = al((size_t)N * 64 * 2);
    char* bufA    = carve(5 * S64);               // 64 MB
    char* bufB    = carve((size_t)N * 304);       // 30.4 MB
    float* Wp     = (float*)carve((size_t)48 * 128 * 4);
    float* b4     = (float*)carve((size_t)128 * 4);
    u16* Wt       = (u16*)carve((size_t)480 * 320 * 2);
    float* b3     = (float*)carve((size_t)480 * 4);
    (void)ws_size;

    u16* X0c  = (u16*)bufA;                                   // N x 10
    u16* T0_1 = (u16*)(bufA + al((size_t)N * 20));            // N x 10
    u16* H0   = (u16*)(bufA + S64);                           // N x 16
    u16* T1_1 = (u16*)(bufA + S64 + al((size_t)N * 32));      // N x 16
    u16* T1_2 = (u16*)(bufA + S64 + 2 * al((size_t)N * 32));  // N x 16
    u16* L2T[4];
    for (int t = 0; t < 4; t++) L2T[t] = (u16*)(bufB + t * al((size_t)N * 64));
    u16* L3T[5];
    for (int t = 0; t < 5; t++) L3T[t] = (u16*)(bufA + t * S64);
    float* part = (float*)bufB;                               // 5 x N x 2 fp32 (4 MB)

    // ---- graph preprocessing ----
    int gE = (E + 255) / 256, gN = (N + 255) / 256;
    int B = (N + 1023) / 1024;
    hipMemsetAsync(cnt, 0, (size_t)N * 4, stream);
    k_count<<<gE, 256, 0, stream>>>(dst, cnt, E);
    k_dinv<<<gN, 256, 0, stream>>>(cnt, dinv, N);
    k_bsum<<<B, 256, 0, stream>>>(cnt, bsum, N);
    k_bscan<<<1, 1024, 0, stream>>>(bsum, boff, row_ptr + N, B);
    k_write<<<B, 256, 0, stream>>>(cnt, boff, row_ptr, cursor, N);
    k_fill<<<gE, 256, 0, stream>>>(src, dst, dinv, cursor, edges, E);

    k_cvt<<<(N * IN_CH + 255) / 256, 256, 0, stream>>>(X0, X0c, N * IN_CH);

    dim3 gv(1, (N + 63) / 64);
    int rb = (N + 127) / 128;

    // spmv shapes: LPN = F/2 lanes per node
    dim3 bs5(5, 48);   int g5 = (N + 47) / 48;
    dim3 bs8(8, 32);   int g8 = (N + 31) / 32;
    dim3 bs16(16, 16); int g16 = (N + 15) / 16;
    dim3 bs32(32, 8);  int g32 = (N + 7) / 8;

    // ---- layer 0: VALU, K=2, Fin=10, F=16 ----
    {
        k_pack_w<<<(20 * 128 + 255) / 256, 256, 0, stream>>>(
            (const float*)d_in[2], (const float*)d_in[10], (const float*)d_in[14], Wp, 20, 16, 128);
        k_pack_b<<<1, 256, 0, stream>>>(
            (const float*)d_in[3], (const float*)d_in[4], (const float*)d_in[5],
            (const float*)d_in[11], (const float*)d_in[12], (const float*)d_in[13],
            (const float*)d_in[15], (const float*)d_in[16], (const float*)d_in[17], b4, 16, 128);
        k_spmv<10><<<g5, bs5, 0, stream>>>(X0c, nullptr, T0_1, row_ptr, edges, N, 1.f);
        TP tp; tp.p[0] = X0c; tp.p[1] = T0_1;
        k_chebgate<u16, 10, 2><<<gv, 256, 0, stream>>>(tp, Wp, b4, H0, N, 16, 128);
    }
    // ---- layer 1: VALU, K=3, Fin=16, F=32 ----
    {
        k_pack_w<<<(48 * 128 + 255) / 256, 256, 0, stream>>>(
            (const float*)d_in[18], (const float*)d_in[26], (const float*)d_in[30], Wp, 48, 32, 128);
        k_pack_b<<<1, 256, 0, stream>>>(
            (const float*)d_in[19], (const float*)d_in[20], (const float*)d_in[21],
            (const float*)d_in[27], (const float*)d_in[28], (const float*)d_in[29],
            (const float*)d_in[31], (const float*)d_in[32], (const float*)d_in[33], b4, 32, 128);
        k_spmv<16><<<g8, bs8, 0, stream>>>(H0, nullptr, T1_1, row_ptr, edges, N, 1.f);
        k_spmv<16><<<g8, bs8, 0, stream>>>(T1_1, H0, T1_2, row_ptr, edges, N, 2.f);
        TP tp; tp.p[0] = H0; tp.p[1] = T1_1; tp.p[2] = T1_2;
        k_chebgate<u16, 16, 3><<<gv, 256, 0, stream>>>(tp, Wp, b4, L2T[0], N, 32, 128);
    }
    // ---- layer 2: MFMA, K=4, Fin=32, F=64 ----
    {
        k_pack_wt<<<(3 * 64 * 128 + 255) / 256, 256, 0, stream>>>(
            (const float*)d_in[34], (const float*)d_in[42], (const float*)d_in[46], Wt, 128, 32, 64, 64);
        k_pack_b3<<<1, 256, 0, stream>>>(
            (const float*)d_in[35], (const float*)d_in[36], (const float*)d_in[37],
            (const float*)d_in[43], (const float*)d_in[44], (const float*)d_in[45],
            (const float*)d_in[47], (const float*)d_in[48], (const float*)d_in[49], b3, 64, 64);
        k_spmv<32><<<g16, bs16, 0, stream>>>(L2T[0], nullptr, L2T[1], row_ptr, edges, N, 1.f);
        k_spmv<32><<<g16, bs16, 0, stream>>>(L2T[1], L2T[0], L2T[2], row_ptr, edges, N, 2.f);
        k_spmv<32><<<g16, bs16, 0, stream>>>(L2T[2], L2T[1], L2T[3], row_ptr, edges, N, 2.f);
        TP tp; for (int t = 0; t < 4; t++) tp.p[t] = L2T[t];
        k_chebgate_mfma<32, 4, 64><<<dim3(rb, 2), 256, 0, stream>>>(tp, Wt, b3, L3T[0], N, 64, 64);
    }
    // ---- layer 3: MFMA + fused final projection, K=5, Fin=64, F=152 ----
    {
        k_pack_wt<<<(3 * 160 * 320 + 255) / 256, 256, 0, stream>>>(
            (const float*)d_in[50], (const float*)d_in[58], (const float*)d_in[62], Wt, 320, 64, 152, 160);
        k_pack_b3<<<2, 256, 0, stream>>>(
            (const float*)d_in[51], (const float*)d_in[52], (const float*)d_in[53],
            (const float*)d_in[59], (const float*)d_in[60], (const float*)d_in[61],
            (const float*)d_in[63], (const float*)d_in[64], (const float*)d_in[65], b3, 152, 160);
        k_spmv<64><<<g32, bs32, 0, stream>>>(L3T[0], nullptr, L3T[1], row_ptr, edges, N, 1.f);
        k_spmv<64><<<g32, bs32, 0, stream>>>(L3T[1], L3T[0], L3T[2], row_ptr, edges, N, 2.f);
        k_spmv<64><<<g32, bs32, 0, stream>>>(L3T[2], L3T[1], L3T[3], row_ptr, edges, N, 2.f);
        k_spmv<64><<<g32, bs32, 0, stream>>>(L3T[3], L3T[2], L3T[4], row_ptr, edges, N, 2.f);
        TP tp; for (int t = 0; t < 5; t++) tp.p[t] = L3T[t];
        k_chebgate_mfma_fused<64, 5, 160><<<dim3(rb, 5), 256, 0, stream>>>(
            tp, Wt, b3, (const float*)d_in[66], part, N, 152);
    }

    k_smax<<<gN, 256, 0, stream>>>(part, (const float*)d_in[67], (float*)d_out, N, 5);
}

// Round 14
// 1247.053 us; speedup vs baseline: 1.1630x; 1.0156x over previous
//
#include <hip/hip_runtime.h>

// GConvLSTM single step x4 layers, H=C=0 => f-gate dead, peepholes dead.
// bf16 storage; chebgate = R10 best (no-LDS, 32-f tiles); L3 fused proj (R12);
// parallel scan (R13). NEW R14:
//  - SpMV unroll x8 WITHOUT NT (first clean test; R7/R9 were NT-confounded),
//  - k_fill bucketed over 8 dst ranges (3.2MB write region per pass -> L2-
//    resident, fewer partial-line evictions; dst/src re-reads are LLC hits).

#define IN_CH 10
typedef unsigned short u16;
typedef unsigned long long u64;
typedef short bf16x8 __attribute__((ext_vector_type(8)));
typedef float f32x4 __attribute__((ext_vector_type(4)));

struct __align__(8) Edge { int s; float w; };

__device__ __forceinline__ float bf2f(u16 u) { return __uint_as_float(((unsigned)u) << 16); }
__device__ __forceinline__ float lo16f(unsigned v) { return __uint_as_float(v << 16); }
__device__ __forceinline__ float hi16f(unsigned v) { return __uint_as_float(v & 0xffff0000u); }
__device__ __forceinline__ u16 f2bf(float f) {
    unsigned x = __float_as_uint(f);
    return (u16)((x + 0x7fff + ((x >> 16) & 1)) >> 16);  // RNE
}
__device__ __forceinline__ float ldv(const float* p) { return *p; }
__device__ __forceinline__ float ldv(const u16* p) { return bf2f(*p); }
__device__ __forceinline__ void stv(float* p, float v) { *p = v; }
__device__ __forceinline__ void stv(u16* p, float v) { *p = f2bf(v); }

// ---------------- graph preprocessing ----------------

__global__ void k_count(const int* __restrict__ dst, int* __restrict__ cnt, int e) {
    int i = blockIdx.x * 256 + threadIdx.x;
    if (i < e) atomicAdd(&cnt[dst[i]], 1);
}

__global__ void k_dinv(const int* __restrict__ cnt, float* __restrict__ dinv, int n) {
    int i = blockIdx.x * 256 + threadIdx.x;
    if (i < n) dinv[i] = cnt[i] > 0 ? rsqrtf((float)cnt[i]) : 0.f;
}

// ---- parallel scan: 1024 elems per 256-thread block ----

__global__ void k_bsum(const int* __restrict__ cnt, int* __restrict__ bsum, int n) {
    __shared__ int red[256];
    int t = threadIdx.x;
    int idx = blockIdx.x * 1024 + t * 4;
    int s = 0;
#pragma unroll
    for (int j = 0; j < 4; j++) s += (idx + j < n) ? cnt[idx + j] : 0;
    red[t] = s;
    __syncthreads();
    for (int off = 128; off > 0; off >>= 1) {
        if (t < off) red[t] += red[t + off];
        __syncthreads();
    }
    if (t == 0) bsum[blockIdx.x] = red[0];
}

__global__ __launch_bounds__(1024) void k_bscan(const int* __restrict__ bsum,
                                                int* __restrict__ boff,
                                                int* __restrict__ total_out, int B) {
    __shared__ int sh[1024];
    int t = threadIdx.x;
    int v = t < B ? bsum[t] : 0;
    sh[t] = v;
    __syncthreads();
    for (int off = 1; off < 1024; off <<= 1) {
        int x = (t >= off) ? sh[t - off] : 0;
        __syncthreads();
        sh[t] += x;
        __syncthreads();
    }
    if (t < B) boff[t] = sh[t] - v;  // exclusive
    if (t == B - 1) *total_out = sh[t];
}

__global__ void k_write(const int* __restrict__ cnt, const int* __restrict__ boff,
                        int* __restrict__ row_ptr, int* __restrict__ cursor, int n) {
    __shared__ int tsum[256];
    int t = threadIdx.x;
    int idx = blockIdx.x * 1024 + t * 4;
    int c[4];
    int s = 0;
#pragma unroll
    for (int j = 0; j < 4; j++) {
        c[j] = (idx + j < n) ? cnt[idx + j] : 0;
        s += c[j];
    }
    tsum[t] = s;
    __syncthreads();
    for (int off = 1; off < 256; off <<= 1) {
        int x = (t >= off) ? tsum[t - off] : 0;
        __syncthreads();
        tsum[t] += x;
        __syncthreads();
    }
    int run = boff[blockIdx.x] + tsum[t] - s;
#pragma unroll
    for (int j = 0; j < 4; j++) {
        if (idx + j < n) {
            row_ptr[idx + j] = run;
            cursor[idx + j] = run;
            run += c[j];
        }
    }
}

// bucketed fill: only edges with dst in [dlo,dhi) write this pass
__global__ void k_fill(const int* __restrict__ src, const int* __restrict__ dst,
                       const float* __restrict__ dinv, int* __restrict__ cursor,
                       Edge* __restrict__ ed, int e, int dlo, int dhi) {
    int i = blockIdx.x * 256 + threadIdx.x;
    if (i >= e) return;
    int d = dst[i];
    if (d < dlo || d >= dhi) return;
    int s = src[i];
    int pos = atomicAdd(&cursor[d], 1);
    float w = dinv[s] * dinv[d];
    u64 v = (u64)(unsigned)s | ((u64)__float_as_uint(w) << 32);
    *(u64*)&ed[pos] = v;
}

// ---------------- Cheb SpMV: full row, unroll x8 (clean, no NT) ----------------

template <int F>
__global__ void k_spmv(const u16* __restrict__ X, const u16* __restrict__ Tprev,
                       u16* __restrict__ Tout, const int* __restrict__ row_ptr,
                       const Edge* __restrict__ ed, int n, float scale) {
    int lane = threadIdx.x;  // [0, F/2)
    int node = blockIdx.x * blockDim.y + threadIdx.y;
    if (node >= n) return;
    int lo = row_ptr[node], hi = row_ptr[node + 1];
    const u16* Xc = X + 2 * lane;
    float a0[4] = {0.f, 0.f, 0.f, 0.f};
    float a1[4] = {0.f, 0.f, 0.f, 0.f};
    int e = lo;
    for (; e + 8 <= hi; e += 8) {
        Edge q[8];
#pragma unroll
        for (int j = 0; j < 8; j++) q[j] = ed[e + j];
        unsigned v[8];
#pragma unroll
        for (int j = 0; j < 8; j++)
            v[j] = *(const unsigned*)(Xc + (size_t)q[j].s * F);
#pragma unroll
        for (int j = 0; j < 8; j++) {
            a0[j & 3] = fmaf(q[j].w, lo16f(v[j]), a0[j & 3]);
            a1[j & 3] = fmaf(q[j].w, hi16f(v[j]), a1[j & 3]);
        }
    }
    for (; e + 4 <= hi; e += 4) {
        Edge q[4];
#pragma unroll
        for (int j = 0; j < 4; j++) q[j] = ed[e + j];
        unsigned v[4];
#pragma unroll
        for (int j = 0; j < 4; j++)
            v[j] = *(const unsigned*)(Xc + (size_t)q[j].s * F);
#pragma unroll
        for (int j = 0; j < 4; j++) {
            a0[j] = fmaf(q[j].w, lo16f(v[j]), a0[j]);
            a1[j] = fmaf(q[j].w, hi16f(v[j]), a1[j]);
        }
    }
    for (; e < hi; e++) {
        Edge q = ed[e];
        unsigned v = *(const unsigned*)(Xc + (size_t)q.s * F);
        a0[0] = fmaf(q.w, lo16f(v), a0[0]);
        a1[0] = fmaf(q.w, hi16f(v), a1[0]);
    }
    float v0 = -scale * ((a0[0] + a0[1]) + (a0[2] + a0[3]));
    float v1 = -scale * ((a1[0] + a1[1]) + (a1[2] + a1[3]));
    if (Tprev) {
        unsigned pv = *(const unsigned*)(Tprev + (size_t)node * F + 2 * lane);
        v0 -= lo16f(pv);
        v1 -= hi16f(pv);
    }
    *(unsigned*)(Tout + (size_t)node * F + 2 * lane) =
        (unsigned)f2bf(v0) | ((unsigned)f2bf(v1) << 16);
}

// ---------------- VALU chebgate (layers 0,1) ----------------
struct TP { const void* p[5]; };

template <typename ST, int FIN, int K>
__global__ __launch_bounds__(256) void k_chebgate(TP tp, const float* __restrict__ Wp,
                                                  const float* __restrict__ b4,
                                                  ST* __restrict__ H, int n, int F,
                                                  int F4pad) {
    __shared__ float As[FIN][68];
    __shared__ float Ws[FIN][128];
    const int tid = threadIdx.x;
    const int fx = tid & 31, ry = tid >> 5;
    const int row0 = blockIdx.y * 64;
    const int f0 = blockIdx.x * 32;
    const int f = f0 + fx;

    float acc[8][3];
    const float4 bv = *(const float4*)&b4[(size_t)f * 4];
#pragma unroll
    for (int r = 0; r < 8; r++) { acc[r][0] = bv.x; acc[r][1] = bv.y; acc[r][2] = bv.z; }

#pragma unroll
    for (int t = 0; t < K; t++) {
        const ST* T = (const ST*)tp.p[t];
        for (int idx = tid; idx < 64 * FIN; idx += 256) {
            int r = idx / FIN, a = idx - r * FIN;
            int rr = row0 + r;
            if (rr >= n) rr = n - 1;
            As[a][r] = ldv(&T[(size_t)rr * FIN + a]);
        }
        const float* Wt = Wp + (size_t)t * FIN * F4pad + (size_t)f0 * 4;
        for (int idx = tid; idx < FIN * 128; idx += 256) {
            int aa = idx >> 7, c = idx & 127;
            Ws[aa][c] = Wt[(size_t)aa * F4pad + c];
        }
        __syncthreads();
#pragma unroll 2
        for (int a = 0; a < FIN; a++) {
            const float4 w = *(const float4*)&Ws[a][fx * 4];
            const float4 x0 = *(const float4*)&As[a][ry * 8];
            const float4 x1 = *(const float4*)&As[a][ry * 8 + 4];
            const float xr[8] = {x0.x, x0.y, x0.z, x0.w, x1.x, x1.y, x1.z, x1.w};
#pragma unroll
            for (int r = 0; r < 8; r++) {
                acc[r][0] = fmaf(xr[r], w.x, acc[r][0]);
                acc[r][1] = fmaf(xr[r], w.y, acc[r][1]);
                acc[r][2] = fmaf(xr[r], w.z, acc[r][2]);
            }
        }
        __syncthreads();
    }

    if (f < F) {
#pragma unroll
        for (int r = 0; r < 8; r++) {
            int row = row0 + ry * 8 + r;
            if (row < n) {
                float gi = 1.f / (1.f + __expf(-acc[r][0]));
                float go = 1.f / (1.f + __expf(-acc[r][2]));
                float c = gi * tanhf(acc[r][1]);
                float h = go * tanhf(c);
                stv(&H[(size_t)row * F + f], fmaxf(h, 0.f));
            }
        }
    }
}

// ---------------- MFMA chebgate (layer 2; R10 best: no LDS, 32-f tiles) ----------------

template <int FIN, int K, int FPAD>
__global__ __launch_bounds__(256) void k_chebgate_mfma(TP tp, const u16* __restrict__ Wt,
                                                       const float* __restrict__ b3,
                                                       u16* __restrict__ H, int n, int F,
                                                       int Hstride) {
    constexpr int KT = K * FIN;
    const int wave = threadIdx.x >> 6;
    const int lane = threadIdx.x & 63;
    const int r0 = blockIdx.x * 128 + wave * 32;
    const int f0 = blockIdx.y * 32;
    const int ln = lane & 15;
    const int lk = lane >> 4;

    f32x4 acc[2][2][3];
#pragma unroll
    for (int rt = 0; rt < 2; rt++)
#pragma unroll
        for (int s = 0; s < 2; s++)
#pragma unroll
            for (int g = 0; g < 3; g++) acc[rt][s][g] = (f32x4){0.f, 0.f, 0.f, 0.f};

    int arow[2];
#pragma unroll
    for (int rt = 0; rt < 2; rt++) {
        int row = r0 + rt * 16 + ln;
        arow[rt] = row < n ? row : n - 1;
    }

    for (int k0 = 0; k0 < KT; k0 += 32) {
        const int t = k0 / FIN;
        const int a0 = k0 % FIN;
        const u16* T = (const u16*)tp.p[t];
        bf16x8 af[2];
#pragma unroll
        for (int rt = 0; rt < 2; rt++)
            af[rt] = *(const bf16x8*)(T + (size_t)arow[rt] * FIN + a0 + lk * 8);
#pragma unroll
        for (int s = 0; s < 2; s++) {
#pragma unroll
            for (int g = 0; g < 3; g++) {
                int col = g * FPAD + f0 + s * 16 + ln;
                bf16x8 bf = *(const bf16x8*)(Wt + (size_t)col * KT + k0 + lk * 8);
#pragma unroll
                for (int rt = 0; rt < 2; rt++)
                    acc[rt][s][g] = __builtin_amdgcn_mfma_f32_16x16x32_bf16(
                        af[rt], bf, acc[rt][s][g], 0, 0, 0);
            }
        }
    }

#pragma unroll
    for (int s = 0; s < 2; s++) {
        int fcol = f0 + s * 16 + ln;
        if (fcol >= F) continue;
        float bi = b3[0 * FPAD + fcol];
        float bc = b3[1 * FPAD + fcol];
        float bo = b3[2 * FPAD + fcol];
#pragma unroll
        for (int rt = 0; rt < 2; rt++) {
#pragma unroll
            for (int reg = 0; reg < 4; reg++) {
                int row = r0 + rt * 16 + lk * 4 + reg;
                if (row < n) {
                    float gi = 1.f / (1.f + __expf(-(acc[rt][s][0][reg] + bi)));
                    float go = 1.f / (1.f + __expf(-(acc[rt][s][2][reg] + bo)));
                    float c = gi * tanhf(acc[rt][s][1][reg] + bc);
                    float h = go * tanhf(c);
                    H[(size_t)row * Hstride + fcol] = f2bf(fmaxf(h, 0.f));
                }
            }
        }
    }
}

// ---------------- MFMA chebgate + fused final projection (layer 3) ----------------

template <int FIN, int K, int FPAD>
__global__ __launch_bounds__(256) void k_chebgate_mfma_fused(
    TP tp, const u16* __restrict__ Wt, const float* __restrict__ b3,
    const float* __restrict__ W2, float* __restrict__ part, int n, int F) {
    constexpr int KT = K * FIN;
    const int wave = threadIdx.x >> 6;
    const int lane = threadIdx.x & 63;
    const int r0 = blockIdx.x * 128 + wave * 32;
    const int f0 = blockIdx.y * 32;
    const int ln = lane & 15;
    const int lk = lane >> 4;

    f32x4 acc[2][2][3];
#pragma unroll
    for (int rt = 0; rt < 2; rt++)
#pragma unroll
        for (int s = 0; s < 2; s++)
#pragma unroll
            for (int g = 0; g < 3; g++) acc[rt][s][g] = (f32x4){0.f, 0.f, 0.f, 0.f};

    int arow[2];
#pragma unroll
    for (int rt = 0; rt < 2; rt++) {
        int row = r0 + rt * 16 + ln;
        arow[rt] = row < n ? row : n - 1;
    }

    for (int k0 = 0; k0 < KT; k0 += 32) {
        const int t = k0 / FIN;
        const int a0 = k0 % FIN;
        const u16* T = (const u16*)tp.p[t];
        bf16x8 af[2];
#pragma unroll
        for (int rt = 0; rt < 2; rt++)
            af[rt] = *(const bf16x8*)(T + (size_t)arow[rt] * FIN + a0 + lk * 8);
#pragma unroll
        for (int s = 0; s < 2; s++) {
#pragma unroll
            for (int g = 0; g < 3; g++) {
                int col = g * FPAD + f0 + s * 16 + ln;
                bf16x8 bf = *(const bf16x8*)(Wt + (size_t)col * KT + k0 + lk * 8);
#pragma unroll
                for (int rt = 0; rt < 2; rt++)
                    acc[rt][s][g] = __builtin_amdgcn_mfma_f32_16x16x32_bf16(
                        af[rt], bf, acc[rt][s][g], 0, 0, 0);
            }
        }
    }

    float p0[2][4], p1[2][4];
#pragma unroll
    for (int rt = 0; rt < 2; rt++)
#pragma unroll
        for (int reg = 0; reg < 4; reg++) { p0[rt][reg] = 0.f; p1[rt][reg] = 0.f; }

#pragma unroll
    for (int s = 0; s < 2; s++) {
        int fcol = f0 + s * 16 + ln;
        float w20 = fcol < F ? W2[fcol * 2 + 0] : 0.f;
        float w21 = fcol < F ? W2[fcol * 2 + 1] : 0.f;
        float bi = b3[0 * FPAD + fcol];
        float bc = b3[1 * FPAD + fcol];
        float bo = b3[2 * FPAD + fcol];
#pragma unroll
        for (int rt = 0; rt < 2; rt++) {
#pragma unroll
            for (int reg = 0; reg < 4; reg++) {
                float gi = 1.f / (1.f + __expf(-(acc[rt][s][0][reg] + bi)));
                float go = 1.f / (1.f + __expf(-(acc[rt][s][2][reg] + bo)));
                float c = gi * tanhf(acc[rt][s][1][reg] + bc);
                float h = fmaxf(go * tanhf(c), 0.f);
                p0[rt][reg] = fmaf(h, w20, p0[rt][reg]);
                p1[rt][reg] = fmaf(h, w21, p1[rt][reg]);
            }
        }
    }

#pragma unroll
    for (int rt = 0; rt < 2; rt++) {
#pragma unroll
        for (int reg = 0; reg < 4; reg++) {
            float v0 = p0[rt][reg], v1 = p1[rt][reg];
#pragma unroll
            for (int m = 1; m <= 8; m <<= 1) {
                v0 += __shfl_xor(v0, m);
                v1 += __shfl_xor(v1, m);
            }
            p0[rt][reg] = v0;
            p1[rt][reg] = v1;
        }
    }

    if (ln == 0) {
        const int tile = blockIdx.y;
#pragma unroll
        for (int rt = 0; rt < 2; rt++) {
#pragma unroll
            for (int reg = 0; reg < 4; reg++) {
                int row = r0 + rt * 16 + lk * 4 + reg;
                if (row < n) {
                    float* pp = part + ((size_t)tile * n + row) * 2;
                    pp[0] = p0[rt][reg];
                    pp[1] = p1[rt][reg];
                }
            }
        }
    }
}

// ---------------- partial-sum + softmax ----------------
__global__ void k_smax(const float* __restrict__ part, const float* __restrict__ b,
                       float* __restrict__ out, int n, int ntiles) {
    int i = blockIdx.x * 256 + threadIdx.x;
    if (i >= n) return;
    float l0 = b[0], l1 = b[1];
    for (int t = 0; t < ntiles; t++) {
        const float* pp = part + ((size_t)t * n + i) * 2;
        l0 += pp[0];
        l1 += pp[1];
    }
    float m = fmaxf(l0, l1);
    float e0 = __expf(l0 - m), e1 = __expf(l1 - m);
    float s = 1.f / (e0 + e1);
    out[(size_t)i * 2 + 0] = e0 * s;
    out[(size_t)i * 2 + 1] = e1 * s;
}

// ---------------- weight/bias packing ----------------

__global__ void k_pack_w(const float* __restrict__ Wi, const float* __restrict__ Wc,
                         const float* __restrict__ Wo, float* __restrict__ Wp,
                         int KFIN, int F, int F4pad) {
    int idx = blockIdx.x * 256 + threadIdx.x;
    int tot = KFIN * F4pad;
    if (idx >= tot) return;
    int c = idx % F4pad;
    int ka = idx / F4pad;
    int f = c >> 2, g = c & 3;
    float v = 0.f;
    if (g < 3 && f < F) {
        const float* Wg = (g == 0) ? Wi : ((g == 1) ? Wc : Wo);
        v = Wg[(size_t)ka * F + f];
    }
    Wp[idx] = v;
}

__global__ void k_pack_b(const float* __restrict__ bxi, const float* __restrict__ bhi,
                         const float* __restrict__ bi, const float* __restrict__ bxc,
                         const float* __restrict__ bhc, const float* __restrict__ bc,
                         const float* __restrict__ bxo, const float* __restrict__ bho,
                         const float* __restrict__ bo, float* __restrict__ b4,
                         int F, int F4pad) {
    int idx = blockIdx.x * 256 + threadIdx.x;
    if (idx >= F4pad) return;
    int f = idx >> 2, g = idx & 3;
    float v = 0.f;
    if (g < 3 && f < F) {
        if (g == 0) v = bxi[f] + bhi[f] + bi[f];
        else if (g == 1) v = bxc[f] + bhc[f] + bc[f];
        else v = bxo[f] + bho[f] + bo[f];
    }
    b4[idx] = v;
}

__global__ void k_pack_wt(const float* __restrict__ Wi, const float* __restrict__ Wc,
                          const float* __restrict__ Wo, u16* __restrict__ Wt,
                          int KT, int Fin, int F, int FPAD) {
    int idx = blockIdx.x * 256 + threadIdx.x;
    int tot = 3 * FPAD * KT;
    if (idx >= tot) return;
    int k = idx % KT;
    int col = idx / KT;
    int g = col / FPAD, f = col % FPAD;
    int t = k / Fin, a = k % Fin;
    float v = 0.f;
    if (f < F) {
        const float* Wg = (g == 0) ? Wi : ((g == 1) ? Wc : Wo);
        v = Wg[((size_t)t * Fin + a) * F + f];
    }
    Wt[idx] = f2bf(v);
}

__global__ void k_pack_b3(const float* __restrict__ bxi, const float* __restrict__ bhi,
                          const float* __restrict__ bi, const float* __restrict__ bxc,
                          const float* __restrict__ bhc, const float* __restrict__ bc,
                          const float* __restrict__ bxo, const float* __restrict__ bho,
                          const float* __restrict__ bo, float* __restrict__ b3,
                          int F, int FPAD) {
    int idx = blockIdx.x * 256 + threadIdx.x;
    if (idx >= 3 * FPAD) return;
    int g = idx / FPAD, f = idx % FPAD;
    float v = 0.f;
    if (f < F) {
        if (g == 0) v = bxi[f] + bhi[f] + bi[f];
        else if (g == 1) v = bxc[f] + bhc[f] + bc[f];
        else v = bxo[f] + bho[f] + bo[f];
    }
    b3[idx] = v;
}

__global__ void k_cvt(const float* __restrict__ x, u16* __restrict__ y, int n) {
    int i = blockIdx.x * 256 + threadIdx.x;
    if (i < n) y[i] = f2bf(x[i]);
}

// ---------------- launch ----------------

static inline size_t al(size_t x) { return (x + 255) & ~(size_t)255; }

extern "C" void kernel_launch(void* const* d_in, const int* in_sizes, int n_in,
                              void* d_out, int out_size, void* d_ws, size_t ws_size,
                              hipStream_t stream) {
    const float* X0 = (const float*)d_in[0];
    const int* ei = (const int*)d_in[1];
    const int N = in_sizes[0] / IN_CH;
    const int E = in_sizes[1] / 2;
    const int* src = ei;
    const int* dst = ei + E;

    // ---- workspace carve (~122 MB) ----
    char* p = (char*)d_ws;
    size_t off = 0;
    auto carve = [&](size_t bytes) -> char* { char* r = p + off; off += al(bytes); return r; };
    int* row_ptr  = (int*)carve((size_t)(N + 1) * 4);
    int* cnt      = (int*)carve((size_t)N * 4);
    int* cursor   = (int*)carve((size_t)N * 4);
    float* dinv   = (float*)carve((size_t)N * 4);
    int* bsum     = (int*)carve((size_t)1024 * 4);
    int* boff     = (int*)carve((size_t)1024 * 4);
    Edge* edges   = (Edge*)carve((size_t)E * 8);
    const size_t S64 = al((size_t)N * 64 * 2);
    char* bufA    = carve(5 * S64);               // 64 MB
    char* bufB    = carve((size_t)N * 304);       // 30.4 MB
    float* Wp     = (float*)carve((size_t)48 * 128 * 4);
    float* b4     = (float*)carve((size_t)128 * 4);
    u16* Wt       = (u16*)carve((size_t)480 * 320 * 2);
    float* b3     = (float*)carve((size_t)480 * 4);
    (void)ws_size;

    u16* X0c  = (u16*)bufA;                                   // N x 10
    u16* T0_1 = (u16*)(bufA + al((size_t)N * 20));            // N x 10
    u16* H0   = (u16*)(bufA + S64);                           // N x 16
    u16* T1_1 = (u16*)(bufA + S64 + al((size_t)N * 32));      // N x 16
    u16* T1_2 = (u16*)(bufA + S64 + 2 * al((size_t)N * 32));  // N x 16
    u16* L2T[4];
    for (int t = 0; t < 4; t++) L2T[t] = (u16*)(bufB + t * al((size_t)N * 64));
    u16* L3T[5];
    for (int t = 0; t < 5; t++) L3T[t] = (u16*)(bufA + t * S64);
    float* part = (float*)bufB;                               // 5 x N x 2 fp32 (4 MB)

    // ---- graph preprocessing ----
    int gE = (E + 255) / 256, gN = (N + 255) / 256;
    int B = (N + 1023) / 1024;
    hipMemsetAsync(cnt, 0, (size_t)N * 4, stream);
    k_count<<<gE, 256, 0, stream>>>(dst, cnt, E);
    k_dinv<<<gN, 256, 0, stream>>>(cnt, dinv, N);
    k_bsum<<<B, 256, 0, stream>>>(cnt, bsum, N);
    k_bscan<<<1, 1024, 0, stream>>>(bsum, boff, row_ptr + N, B);
    k_write<<<B, 256, 0, stream>>>(cnt, boff, row_ptr, cursor, N);
    const int NB = 8;
    for (int b = 0; b < NB; b++) {
        int dlo = (int)((long long)N * b / NB);
        int dhi = (int)((long long)N * (b + 1) / NB);
        k_fill<<<gE, 256, 0, stream>>>(src, dst, dinv, cursor, edges, E, dlo, dhi);
    }

    k_cvt<<<(N * IN_CH + 255) / 256, 256, 0, stream>>>(X0, X0c, N * IN_CH);

    dim3 gv(1, (N + 63) / 64);
    int rb = (N + 127) / 128;

    // spmv shapes: LPN = F/2 lanes per node
    dim3 bs5(5, 48);   int g5 = (N + 47) / 48;
    dim3 bs8(8, 32);   int g8 = (N + 31) / 32;
    dim3 bs16(16, 16); int g16 = (N + 15) / 16;
    dim3 bs32(32, 8);  int g32 = (N + 7) / 8;

    // ---- layer 0: VALU, K=2, Fin=10, F=16 ----
    {
        k_pack_w<<<(20 * 128 + 255) / 256, 256, 0, stream>>>(
            (const float*)d_in[2], (const float*)d_in[10], (const float*)d_in[14], Wp, 20, 16, 128);
        k_pack_b<<<1, 256, 0, stream>>>(
            (const float*)d_in[3], (const float*)d_in[4], (const float*)d_in[5],
            (const float*)d_in[11], (const float*)d_in[12], (const float*)d_in[13],
            (const float*)d_in[15], (const float*)d_in[16], (const float*)d_in[17], b4, 16, 128);
        k_spmv<10><<<g5, bs5, 0, stream>>>(X0c, nullptr, T0_1, row_ptr, edges, N, 1.f);
        TP tp; tp.p[0] = X0c; tp.p[1] = T0_1;
        k_chebgate<u16, 10, 2><<<gv, 256, 0, stream>>>(tp, Wp, b4, H0, N, 16, 128);
    }
    // ---- layer 1: VALU, K=3, Fin=16, F=32 ----
    {
        k_pack_w<<<(48 * 128 + 255) / 256, 256, 0, stream>>>(
            (const float*)d_in[18], (const float*)d_in[26], (const float*)d_in[30], Wp, 48, 32, 128);
        k_pack_b<<<1, 256, 0, stream>>>(
            (const float*)d_in[19], (const float*)d_in[20], (const float*)d_in[21],
            (const float*)d_in[27], (const float*)d_in[28], (const float*)d_in[29],
            (const float*)d_in[31], (const float*)d_in[32], (const float*)d_in[33], b4, 32, 128);
        k_spmv<16><<<g8, bs8, 0, stream>>>(H0, nullptr, T1_1, row_ptr, edges, N, 1.f);
        k_spmv<16><<<g8, bs8, 0, stream>>>(T1_1, H0, T1_2, row_ptr, edges, N, 2.f);
        TP tp; tp.p[0] = H0; tp.p[1] = T1_1; tp.p[2] = T1_2;
        k_chebgate<u16, 16, 3><<<gv, 256, 0, stream>>>(tp, Wp, b4, L2T[0], N, 32, 128);
    }
    // ---- layer 2: MFMA, K=4, Fin=32, F=64 ----
    {
        k_pack_wt<<<(3 * 64 * 128 + 255) / 256, 256, 0, stream>>>(
            (const float*)d_in[34], (const float*)d_in[42], (const float*)d_in[46], Wt, 128, 32, 64, 64);
        k_pack_b3<<<1, 256, 0, stream>>>(
            (const float*)d_in[35], (const float*)d_in[36], (const float*)d_in[37],
            (const float*)d_in[43], (const float*)d_in[44], (const float*)d_in[45],
            (const float*)d_in[47], (const float*)d_in[48], (const float*)d_in[49], b3, 64, 64);
        k_spmv<32><<<g16, bs16, 0, stream>>>(L2T[0], nullptr, L2T[1], row_ptr, edges, N, 1.f);
        k_spmv<32><<<g16, bs16, 0, stream>>>(L2T[1], L2T[0], L2T[2], row_ptr, edges, N, 2.f);
        k_spmv<32><<<g16, bs16, 0, stream>>>(L2T[2], L2T[1], L2T[3], row_ptr, edges, N, 2.f);
        TP tp; for (int t = 0; t < 4; t++) tp.p[t] = L2T[t];
        k_chebgate_mfma<32, 4, 64><<<dim3(rb, 2), 256, 0, stream>>>(tp, Wt, b3, L3T[0], N, 64, 64);
    }
    // ---- layer 3: MFMA + fused final projection, K=5, Fin=64, F=152 ----
    {
        k_pack_wt<<<(3 * 160 * 320 + 255) / 256, 256, 0, stream>>>(
            (const float*)d_in[50], (const float*)d_in[58], (const float*)d_in[62], Wt, 320, 64, 152, 160);
        k_pack_b3<<<2, 256, 0, stream>>>(
            (const float*)d_in[51], (const float*)d_in[52], (const float*)d_in[53],
            (const float*)d_in[59], (const float*)d_in[60], (const float*)d_in[61],
            (const float*)d_in[63], (const float*)d_in[64], (const float*)d_in[65], b3, 152, 160);
        k_spmv<64><<<g32, bs32, 0, stream>>>(L3T[0], nullptr, L3T[1], row_ptr, edges, N, 1.f);
        k_spmv<64><<<g32, bs32, 0, stream>>>(L3T[1], L3T[0], L3T[2], row_ptr, edges, N, 2.f);
        k_spmv<64><<<g32, bs32, 0, stream>>>(L3T[2], L3T[1], L3T[3], row_ptr, edges, N, 2.f);
        k_spmv<64><<<g32, bs32, 0, stream>>>(L3T[3], L3T[2], L3T[4], row_ptr, edges, N, 2.f);
        TP tp; for (int t = 0; t < 5; t++) tp.p[t] = L3T[t];
        k_chebgate_mfma_fused<64, 5, 160><<<dim3(rb, 5), 256, 0, stream>>>(
            tp, Wt, b3, (const float*)d_in[66], part, N, 152);
    }

    k_smax<<<gN, 256, 0, stream>>>(part, (const float*)d_in[67], (float*)d_out, N, 5);
}

// Round 15
// 1241.205 us; speedup vs baseline: 1.1685x; 1.0047x over previous
//
#include <hip/hip_runtime.h>

// GConvLSTM single step x4 layers, H=C=0 => f-gate dead, peepholes dead.
// bf16 storage; chebgate = R10 best (no-LDS, 32-f tiles); L3 fused proj (R12);
// parallel scan (R13); bucketed fill + spmv unroll8 (R14). NEW R15:
//  - MFMA chebgates use a FLATTENED 1-D grid, x=bidx/NT, y=bidx%NT: the NT
//    f-tile blocks reading the same A row-block become temporally adjacent in
//    dispatch order -> LLC-hit for NT-1 of NT sweeps (R14 counters: x-major
//    order re-fetched A from HBM, FETCH=158MB ~ 2.5x the 64MB A-concat).

#define IN_CH 10
typedef unsigned short u16;
typedef unsigned long long u64;
typedef short bf16x8 __attribute__((ext_vector_type(8)));
typedef float f32x4 __attribute__((ext_vector_type(4)));

struct __align__(8) Edge { int s; float w; };

__device__ __forceinline__ float bf2f(u16 u) { return __uint_as_float(((unsigned)u) << 16); }
__device__ __forceinline__ float lo16f(unsigned v) { return __uint_as_float(v << 16); }
__device__ __forceinline__ float hi16f(unsigned v) { return __uint_as_float(v & 0xffff0000u); }
__device__ __forceinline__ u16 f2bf(float f) {
    unsigned x = __float_as_uint(f);
    return (u16)((x + 0x7fff + ((x >> 16) & 1)) >> 16);  // RNE
}
__device__ __forceinline__ float ldv(const float* p) { return *p; }
__device__ __forceinline__ float ldv(const u16* p) { return bf2f(*p); }
__device__ __forceinline__ void stv(float* p, float v) { *p = v; }
__device__ __forceinline__ void stv(u16* p, float v) { *p = f2bf(v); }

// ---------------- graph preprocessing ----------------

__global__ void k_count(const int* __restrict__ dst, int* __restrict__ cnt, int e) {
    int i = blockIdx.x * 256 + threadIdx.x;
    if (i < e) atomicAdd(&cnt[dst[i]], 1);
}

__global__ void k_dinv(const int* __restrict__ cnt, float* __restrict__ dinv, int n) {
    int i = blockIdx.x * 256 + threadIdx.x;
    if (i < n) dinv[i] = cnt[i] > 0 ? rsqrtf((float)cnt[i]) : 0.f;
}

// ---- parallel scan: 1024 elems per 256-thread block ----

__global__ void k_bsum(const int* __restrict__ cnt, int* __restrict__ bsum, int n) {
    __shared__ int red[256];
    int t = threadIdx.x;
    int idx = blockIdx.x * 1024 + t * 4;
    int s = 0;
#pragma unroll
    for (int j = 0; j < 4; j++) s += (idx + j < n) ? cnt[idx + j] : 0;
    red[t] = s;
    __syncthreads();
    for (int off = 128; off > 0; off >>= 1) {
        if (t < off) red[t] += red[t + off];
        __syncthreads();
    }
    if (t == 0) bsum[blockIdx.x] = red[0];
}

__global__ __launch_bounds__(1024) void k_bscan(const int* __restrict__ bsum,
                                                int* __restrict__ boff,
                                                int* __restrict__ total_out, int B) {
    __shared__ int sh[1024];
    int t = threadIdx.x;
    int v = t < B ? bsum[t] : 0;
    sh[t] = v;
    __syncthreads();
    for (int off = 1; off < 1024; off <<= 1) {
        int x = (t >= off) ? sh[t - off] : 0;
        __syncthreads();
        sh[t] += x;
        __syncthreads();
    }
    if (t < B) boff[t] = sh[t] - v;  // exclusive
    if (t == B - 1) *total_out = sh[t];
}

__global__ void k_write(const int* __restrict__ cnt, const int* __restrict__ boff,
                        int* __restrict__ row_ptr, int* __restrict__ cursor, int n) {
    __shared__ int tsum[256];
    int t = threadIdx.x;
    int idx = blockIdx.x * 1024 + t * 4;
    int c[4];
    int s = 0;
#pragma unroll
    for (int j = 0; j < 4; j++) {
        c[j] = (idx + j < n) ? cnt[idx + j] : 0;
        s += c[j];
    }
    tsum[t] = s;
    __syncthreads();
    for (int off = 1; off < 256; off <<= 1) {
        int x = (t >= off) ? tsum[t - off] : 0;
        __syncthreads();
        tsum[t] += x;
        __syncthreads();
    }
    int run = boff[blockIdx.x] + tsum[t] - s;
#pragma unroll
    for (int j = 0; j < 4; j++) {
        if (idx + j < n) {
            row_ptr[idx + j] = run;
            cursor[idx + j] = run;
            run += c[j];
        }
    }
}

// bucketed fill: only edges with dst in [dlo,dhi) write this pass
__global__ void k_fill(const int* __restrict__ src, const int* __restrict__ dst,
                       const float* __restrict__ dinv, int* __restrict__ cursor,
                       Edge* __restrict__ ed, int e, int dlo, int dhi) {
    int i = blockIdx.x * 256 + threadIdx.x;
    if (i >= e) return;
    int d = dst[i];
    if (d < dlo || d >= dhi) return;
    int s = src[i];
    int pos = atomicAdd(&cursor[d], 1);
    float w = dinv[s] * dinv[d];
    u64 v = (u64)(unsigned)s | ((u64)__float_as_uint(w) << 32);
    *(u64*)&ed[pos] = v;
}

// ---------------- Cheb SpMV: full row, unroll x8 ----------------

template <int F>
__global__ void k_spmv(const u16* __restrict__ X, const u16* __restrict__ Tprev,
                       u16* __restrict__ Tout, const int* __restrict__ row_ptr,
                       const Edge* __restrict__ ed, int n, float scale) {
    int lane = threadIdx.x;  // [0, F/2)
    int node = blockIdx.x * blockDim.y + threadIdx.y;
    if (node >= n) return;
    int lo = row_ptr[node], hi = row_ptr[node + 1];
    const u16* Xc = X + 2 * lane;
    float a0[4] = {0.f, 0.f, 0.f, 0.f};
    float a1[4] = {0.f, 0.f, 0.f, 0.f};
    int e = lo;
    for (; e + 8 <= hi; e += 8) {
        Edge q[8];
#pragma unroll
        for (int j = 0; j < 8; j++) q[j] = ed[e + j];
        unsigned v[8];
#pragma unroll
        for (int j = 0; j < 8; j++)
            v[j] = *(const unsigned*)(Xc + (size_t)q[j].s * F);
#pragma unroll
        for (int j = 0; j < 8; j++) {
            a0[j & 3] = fmaf(q[j].w, lo16f(v[j]), a0[j & 3]);
            a1[j & 3] = fmaf(q[j].w, hi16f(v[j]), a1[j & 3]);
        }
    }
    for (; e + 4 <= hi; e += 4) {
        Edge q[4];
#pragma unroll
        for (int j = 0; j < 4; j++) q[j] = ed[e + j];
        unsigned v[4];
#pragma unroll
        for (int j = 0; j < 4; j++)
            v[j] = *(const unsigned*)(Xc + (size_t)q[j].s * F);
#pragma unroll
        for (int j = 0; j < 4; j++) {
            a0[j] = fmaf(q[j].w, lo16f(v[j]), a0[j]);
            a1[j] = fmaf(q[j].w, hi16f(v[j]), a1[j]);
        }
    }
    for (; e < hi; e++) {
        Edge q = ed[e];
        unsigned v = *(const unsigned*)(Xc + (size_t)q.s * F);
        a0[0] = fmaf(q.w, lo16f(v), a0[0]);
        a1[0] = fmaf(q.w, hi16f(v), a1[0]);
    }
    float v0 = -scale * ((a0[0] + a0[1]) + (a0[2] + a0[3]));
    float v1 = -scale * ((a1[0] + a1[1]) + (a1[2] + a1[3]));
    if (Tprev) {
        unsigned pv = *(const unsigned*)(Tprev + (size_t)node * F + 2 * lane);
        v0 -= lo16f(pv);
        v1 -= hi16f(pv);
    }
    *(unsigned*)(Tout + (size_t)node * F + 2 * lane) =
        (unsigned)f2bf(v0) | ((unsigned)f2bf(v1) << 16);
}

// ---------------- VALU chebgate (layers 0,1) ----------------
struct TP { const void* p[5]; };

template <typename ST, int FIN, int K>
__global__ __launch_bounds__(256) void k_chebgate(TP tp, const float* __restrict__ Wp,
                                                  const float* __restrict__ b4,
                                                  ST* __restrict__ H, int n, int F,
                                                  int F4pad) {
    __shared__ float As[FIN][68];
    __shared__ float Ws[FIN][128];
    const int tid = threadIdx.x;
    const int fx = tid & 31, ry = tid >> 5;
    const int row0 = blockIdx.y * 64;
    const int f0 = blockIdx.x * 32;
    const int f = f0 + fx;

    float acc[8][3];
    const float4 bv = *(const float4*)&b4[(size_t)f * 4];
#pragma unroll
    for (int r = 0; r < 8; r++) { acc[r][0] = bv.x; acc[r][1] = bv.y; acc[r][2] = bv.z; }

#pragma unroll
    for (int t = 0; t < K; t++) {
        const ST* T = (const ST*)tp.p[t];
        for (int idx = tid; idx < 64 * FIN; idx += 256) {
            int r = idx / FIN, a = idx - r * FIN;
            int rr = row0 + r;
            if (rr >= n) rr = n - 1;
            As[a][r] = ldv(&T[(size_t)rr * FIN + a]);
        }
        const float* Wt = Wp + (size_t)t * FIN * F4pad + (size_t)f0 * 4;
        for (int idx = tid; idx < FIN * 128; idx += 256) {
            int aa = idx >> 7, c = idx & 127;
            Ws[aa][c] = Wt[(size_t)aa * F4pad + c];
        }
        __syncthreads();
#pragma unroll 2
        for (int a = 0; a < FIN; a++) {
            const float4 w = *(const float4*)&Ws[a][fx * 4];
            const float4 x0 = *(const float4*)&As[a][ry * 8];
            const float4 x1 = *(const float4*)&As[a][ry * 8 + 4];
            const float xr[8] = {x0.x, x0.y, x0.z, x0.w, x1.x, x1.y, x1.z, x1.w};
#pragma unroll
            for (int r = 0; r < 8; r++) {
                acc[r][0] = fmaf(xr[r], w.x, acc[r][0]);
                acc[r][1] = fmaf(xr[r], w.y, acc[r][1]);
                acc[r][2] = fmaf(xr[r], w.z, acc[r][2]);
            }
        }
        __syncthreads();
    }

    if (f < F) {
#pragma unroll
        for (int r = 0; r < 8; r++) {
            int row = row0 + ry * 8 + r;
            if (row < n) {
                float gi = 1.f / (1.f + __expf(-acc[r][0]));
                float go = 1.f / (1.f + __expf(-acc[r][2]));
                float c = gi * tanhf(acc[r][1]);
                float h = go * tanhf(c);
                stv(&H[(size_t)row * F + f], fmaxf(h, 0.f));
            }
        }
    }
}

// ---------------- MFMA chebgate (layer 2): 1-D grid, tile-adjacent order ----------------

template <int FIN, int K, int FPAD, int NT>
__global__ __launch_bounds__(256) void k_chebgate_mfma(TP tp, const u16* __restrict__ Wt,
                                                       const float* __restrict__ b3,
                                                       u16* __restrict__ H, int n, int F,
                                                       int Hstride) {
    constexpr int KT = K * FIN;
    const int xb = blockIdx.x / NT;     // row-block
    const int yb = blockIdx.x % NT;     // f-tile (adjacent in dispatch order)
    const int wave = threadIdx.x >> 6;
    const int lane = threadIdx.x & 63;
    const int r0 = xb * 128 + wave * 32;
    const int f0 = yb * 32;
    const int ln = lane & 15;
    const int lk = lane >> 4;

    f32x4 acc[2][2][3];
#pragma unroll
    for (int rt = 0; rt < 2; rt++)
#pragma unroll
        for (int s = 0; s < 2; s++)
#pragma unroll
            for (int g = 0; g < 3; g++) acc[rt][s][g] = (f32x4){0.f, 0.f, 0.f, 0.f};

    int arow[2];
#pragma unroll
    for (int rt = 0; rt < 2; rt++) {
        int row = r0 + rt * 16 + ln;
        arow[rt] = row < n ? row : n - 1;
    }

    for (int k0 = 0; k0 < KT; k0 += 32) {
        const int t = k0 / FIN;
        const int a0 = k0 % FIN;
        const u16* T = (const u16*)tp.p[t];
        bf16x8 af[2];
#pragma unroll
        for (int rt = 0; rt < 2; rt++)
            af[rt] = *(const bf16x8*)(T + (size_t)arow[rt] * FIN + a0 + lk * 8);
#pragma unroll
        for (int s = 0; s < 2; s++) {
#pragma unroll
            for (int g = 0; g < 3; g++) {
                int col = g * FPAD + f0 + s * 16 + ln;
                bf16x8 bf = *(const bf16x8*)(Wt + (size_t)col * KT + k0 + lk * 8);
#pragma unroll
                for (int rt = 0; rt < 2; rt++)
                    acc[rt][s][g] = __builtin_amdgcn_mfma_f32_16x16x32_bf16(
                        af[rt], bf, acc[rt][s][g], 0, 0, 0);
            }
        }
    }

#pragma unroll
    for (int s = 0; s < 2; s++) {
        int fcol = f0 + s * 16 + ln;
        if (fcol >= F) continue;
        float bi = b3[0 * FPAD + fcol];
        float bc = b3[1 * FPAD + fcol];
        float bo = b3[2 * FPAD + fcol];
#pragma unroll
        for (int rt = 0; rt < 2; rt++) {
#pragma unroll
            for (int reg = 0; reg < 4; reg++) {
                int row = r0 + rt * 16 + lk * 4 + reg;
                if (row < n) {
                    float gi = 1.f / (1.f + __expf(-(acc[rt][s][0][reg] + bi)));
                    float go = 1.f / (1.f + __expf(-(acc[rt][s][2][reg] + bo)));
                    float c = gi * tanhf(acc[rt][s][1][reg] + bc);
                    float h = go * tanhf(c);
                    H[(size_t)row * Hstride + fcol] = f2bf(fmaxf(h, 0.f));
                }
            }
        }
    }
}

// ---------------- MFMA chebgate + fused final projection (layer 3) ----------------

template <int FIN, int K, int FPAD, int NT>
__global__ __launch_bounds__(256) void k_chebgate_mfma_fused(
    TP tp, const u16* __restrict__ Wt, const float* __restrict__ b3,
    const float* __restrict__ W2, float* __restrict__ part, int n, int F) {
    constexpr int KT = K * FIN;
    const int xb = blockIdx.x / NT;
    const int yb = blockIdx.x % NT;
    const int wave = threadIdx.x >> 6;
    const int lane = threadIdx.x & 63;
    const int r0 = xb * 128 + wave * 32;
    const int f0 = yb * 32;
    const int ln = lane & 15;
    const int lk = lane >> 4;

    f32x4 acc[2][2][3];
#pragma unroll
    for (int rt = 0; rt < 2; rt++)
#pragma unroll
        for (int s = 0; s < 2; s++)
#pragma unroll
            for (int g = 0; g < 3; g++) acc[rt][s][g] = (f32x4){0.f, 0.f, 0.f, 0.f};

    int arow[2];
#pragma unroll
    for (int rt = 0; rt < 2; rt++) {
        int row = r0 + rt * 16 + ln;
        arow[rt] = row < n ? row : n - 1;
    }

    for (int k0 = 0; k0 < KT; k0 += 32) {
        const int t = k0 / FIN;
        const int a0 = k0 % FIN;
        const u16* T = (const u16*)tp.p[t];
        bf16x8 af[2];
#pragma unroll
        for (int rt = 0; rt < 2; rt++)
            af[rt] = *(const bf16x8*)(T + (size_t)arow[rt] * FIN + a0 + lk * 8);
#pragma unroll
        for (int s = 0; s < 2; s++) {
#pragma unroll
            for (int g = 0; g < 3; g++) {
                int col = g * FPAD + f0 + s * 16 + ln;
                bf16x8 bf = *(const bf16x8*)(Wt + (size_t)col * KT + k0 + lk * 8);
#pragma unroll
                for (int rt = 0; rt < 2; rt++)
                    acc[rt][s][g] = __builtin_amdgcn_mfma_f32_16x16x32_bf16(
                        af[rt], bf, acc[rt][s][g], 0, 0, 0);
            }
        }
    }

    float p0[2][4], p1[2][4];
#pragma unroll
    for (int rt = 0; rt < 2; rt++)
#pragma unroll
        for (int reg = 0; reg < 4; reg++) { p0[rt][reg] = 0.f; p1[rt][reg] = 0.f; }

#pragma unroll
    for (int s = 0; s < 2; s++) {
        int fcol = f0 + s * 16 + ln;
        float w20 = fcol < F ? W2[fcol * 2 + 0] : 0.f;
        float w21 = fcol < F ? W2[fcol * 2 + 1] : 0.f;
        float bi = b3[0 * FPAD + fcol];
        float bc = b3[1 * FPAD + fcol];
        float bo = b3[2 * FPAD + fcol];
#pragma unroll
        for (int rt = 0; rt < 2; rt++) {
#pragma unroll
            for (int reg = 0; reg < 4; reg++) {
                float gi = 1.f / (1.f + __expf(-(acc[rt][s][0][reg] + bi)));
                float go = 1.f / (1.f + __expf(-(acc[rt][s][2][reg] + bo)));
                float c = gi * tanhf(acc[rt][s][1][reg] + bc);
                float h = fmaxf(go * tanhf(c), 0.f);
                p0[rt][reg] = fmaf(h, w20, p0[rt][reg]);
                p1[rt][reg] = fmaf(h, w21, p1[rt][reg]);
            }
        }
    }

#pragma unroll
    for (int rt = 0; rt < 2; rt++) {
#pragma unroll
        for (int reg = 0; reg < 4; reg++) {
            float v0 = p0[rt][reg], v1 = p1[rt][reg];
#pragma unroll
            for (int m = 1; m <= 8; m <<= 1) {
                v0 += __shfl_xor(v0, m);
                v1 += __shfl_xor(v1, m);
            }
            p0[rt][reg] = v0;
            p1[rt][reg] = v1;
        }
    }

    if (ln == 0) {
#pragma unroll
        for (int rt = 0; rt < 2; rt++) {
#pragma unroll
            for (int reg = 0; reg < 4; reg++) {
                int row = r0 + rt * 16 + lk * 4 + reg;
                if (row < n) {
                    float* pp = part + ((size_t)yb * n + row) * 2;
                    pp[0] = p0[rt][reg];
                    pp[1] = p1[rt][reg];
                }
            }
        }
    }
}

// ---------------- partial-sum + softmax ----------------
__global__ void k_smax(const float* __restrict__ part, const float* __restrict__ b,
                       float* __restrict__ out, int n, int ntiles) {
    int i = blockIdx.x * 256 + threadIdx.x;
    if (i >= n) return;
    float l0 = b[0], l1 = b[1];
    for (int t = 0; t < ntiles; t++) {
        const float* pp = part + ((size_t)t * n + i) * 2;
        l0 += pp[0];
        l1 += pp[1];
    }
    float m = fmaxf(l0, l1);
    float e0 = __expf(l0 - m), e1 = __expf(l1 - m);
    float s = 1.f / (e0 + e1);
    out[(size_t)i * 2 + 0] = e0 * s;
    out[(size_t)i * 2 + 1] = e1 * s;
}

// ---------------- weight/bias packing ----------------

__global__ void k_pack_w(const float* __restrict__ Wi, const float* __restrict__ Wc,
                         const float* __restrict__ Wo, float* __restrict__ Wp,
                         int KFIN, int F, int F4pad) {
    int idx = blockIdx.x * 256 + threadIdx.x;
    int tot = KFIN * F4pad;
    if (idx >= tot) return;
    int c = idx % F4pad;
    int ka = idx / F4pad;
    int f = c >> 2, g = c & 3;
    float v = 0.f;
    if (g < 3 && f < F) {
        const float* Wg = (g == 0) ? Wi : ((g == 1) ? Wc : Wo);
        v = Wg[(size_t)ka * F + f];
    }
    Wp[idx] = v;
}

__global__ void k_pack_b(const float* __restrict__ bxi, const float* __restrict__ bhi,
                         const float* __restrict__ bi, const float* __restrict__ bxc,
                         const float* __restrict__ bhc, const float* __restrict__ bc,
                         const float* __restrict__ bxo, const float* __restrict__ bho,
                         const float* __restrict__ bo, float* __restrict__ b4,
                         int F, int F4pad) {
    int idx = blockIdx.x * 256 + threadIdx.x;
    if (idx >= F4pad) return;
    int f = idx >> 2, g = idx & 3;
    float v = 0.f;
    if (g < 3 && f < F) {
        if (g == 0) v = bxi[f] + bhi[f] + bi[f];
        else if (g == 1) v = bxc[f] + bhc[f] + bc[f];
        else v = bxo[f] + bho[f] + bo[f];
    }
    b4[idx] = v;
}

__global__ void k_pack_wt(const float* __restrict__ Wi, const float* __restrict__ Wc,
                          const float* __restrict__ Wo, u16* __restrict__ Wt,
                          int KT, int Fin, int F, int FPAD) {
    int idx = blockIdx.x * 256 + threadIdx.x;
    int tot = 3 * FPAD * KT;
    if (idx >= tot) return;
    int k = idx % KT;
    int col = idx / KT;
    int g = col / FPAD, f = col % FPAD;
    int t = k / Fin, a = k % Fin;
    float v = 0.f;
    if (f < F) {
        const float* Wg = (g == 0) ? Wi : ((g == 1) ? Wc : Wo);
        v = Wg[((size_t)t * Fin + a) * F + f];
    }
    Wt[idx] = f2bf(v);
}

__global__ void k_pack_b3(const float* __restrict__ bxi, const float* __restrict__ bhi,
                          const float* __restrict__ bi, const float* __restrict__ bxc,
                          const float* __restrict__ bhc, const float* __restrict__ bc,
                          const float* __restrict__ bxo, const float* __restrict__ bho,
                          const float* __restrict__ bo, float* __restrict__ b3,
                          int F, int FPAD) {
    int idx = blockIdx.x * 256 + threadIdx.x;
    if (idx >= 3 * FPAD) return;
    int g = idx / FPAD, f = idx % FPAD;
    float v = 0.f;
    if (f < F) {
        if (g == 0) v = bxi[f] + bhi[f] + bi[f];
        else if (g == 1) v = bxc[f] + bhc[f] + bc[f];
        else v = bxo[f] + bho[f] + bo[f];
    }
    b3[idx] = v;
}

__global__ void k_cvt(const float* __restrict__ x, u16* __restrict__ y, int n) {
    int i = blockIdx.x * 256 + threadIdx.x;
    if (i < n) y[i] = f2bf(x[i]);
}

// ---------------- launch ----------------

static inline size_t al(size_t x) { return (x + 255) & ~(size_t)255; }

extern "C" void kernel_launch(void* const* d_in, const int* in_sizes, int n_in,
                              void* d_out, int out_size, void* d_ws, size_t ws_size,
                              hipStream_t stream) {
    const float* X0 = (const float*)d_in[0];
    const int* ei = (const int*)d_in[1];
    const int N = in_sizes[0] / IN_CH;
    const int E = in_sizes[1] / 2;
    const int* src = ei;
    const int* dst = ei + E;

    // ---- workspace carve (~122 MB) ----
    char* p = (char*)d_ws;
    size_t off = 0;
    auto carve = [&](size_t bytes) -> char* { char* r = p + off; off += al(bytes); return r; };
    int* row_ptr  = (int*)carve((size_t)(N + 1) * 4);
    int* cnt      = (int*)carve((size_t)N * 4);
    int* cursor   = (int*)carve((size_t)N * 4);
    float* dinv   = (float*)carve((size_t)N * 4);
    int* bsum     = (int*)carve((size_t)1024 * 4);
    int* boff     = (int*)carve((size_t)1024 * 4);
    Edge* edges   = (Edge*)carve((size_t)E * 8);
    const size_t S64 = al((size_t)N * 64 * 2);
    char* bufA    = carve(5 * S64);               // 64 MB
    char* bufB    = carve((size_t)N * 304);       // 30.4 MB
    float* Wp     = (float*)carve((size_t)48 * 128 * 4);
    float* b4     = (float*)carve((size_t)128 * 4);
    u16* Wt       = (u16*)carve((size_t)480 * 320 * 2);
    float* b3     = (float*)carve((size_t)480 * 4);
    (void)ws_size;

    u16* X0c  = (u16*)bufA;                                   // N x 10
    u16* T0_1 = (u16*)(bufA + al((size_t)N * 20));            // N x 10
    u16* H0   = (u16*)(bufA + S64);                           // N x 16
    u16* T1_1 = (u16*)(bufA + S64 + al((size_t)N * 32));      // N x 16
    u16* T1_2 = (u16*)(bufA + S64 + 2 * al((size_t)N * 32));  // N x 16
    u16* L2T[4];
    for (int t = 0; t < 4; t++) L2T[t] = (u16*)(bufB + t * al((size_t)N * 64));
    u16* L3T[5];
    for (int t = 0; t < 5; t++) L3T[t] = (u16*)(bufA + t * S64);
    float* part = (float*)bufB;                               // 5 x N x 2 fp32 (4 MB)

    // ---- graph preprocessing ----
    int gE = (E + 255) / 256, gN = (N + 255) / 256;
    int B = (N + 1023) / 1024;
    hipMemsetAsync(cnt, 0, (size_t)N * 4, stream);
    k_count<<<gE, 256, 0, stream>>>(dst, cnt, E);
    k_dinv<<<gN, 256, 0, stream>>>(cnt, dinv, N);
    k_bsum<<<B, 256, 0, stream>>>(cnt, bsum, N);
    k_bscan<<<1, 1024, 0, stream>>>(bsum, boff, row_ptr + N, B);
    k_write<<<B, 256, 0, stream>>>(cnt, boff, row_ptr, cursor, N);
    const int NB = 8;
    for (int b = 0; b < NB; b++) {
        int dlo = (int)((long long)N * b / NB);
        int dhi = (int)((long long)N * (b + 1) / NB);
        k_fill<<<gE, 256, 0, stream>>>(src, dst, dinv, cursor, edges, E, dlo, dhi);
    }

    k_cvt<<<(N * IN_CH + 255) / 256, 256, 0, stream>>>(X0, X0c, N * IN_CH);

    dim3 gv(1, (N + 63) / 64);
    int rb = (N + 127) / 128;

    // spmv shapes: LPN = F/2 lanes per node
    dim3 bs5(5, 48);   int g5 = (N + 47) / 48;
    dim3 bs8(8, 32);   int g8 = (N + 31) / 32;
    dim3 bs16(16, 16); int g16 = (N + 15) / 16;
    dim3 bs32(32, 8);  int g32 = (N + 7) / 8;

    // ---- layer 0: VALU, K=2, Fin=10, F=16 ----
    {
        k_pack_w<<<(20 * 128 + 255) / 256, 256, 0, stream>>>(
            (const float*)d_in[2], (const float*)d_in[10], (const float*)d_in[14], Wp, 20, 16, 128);
        k_pack_b<<<1, 256, 0, stream>>>(
            (const float*)d_in[3], (const float*)d_in[4], (const float*)d_in[5],
            (const float*)d_in[11], (const float*)d_in[12], (const float*)d_in[13],
            (const float*)d_in[15], (const float*)d_in[16], (const float*)d_in[17], b4, 16, 128);
        k_spmv<10><<<g5, bs5, 0, stream>>>(X0c, nullptr, T0_1, row_ptr, edges, N, 1.f);
        TP tp; tp.p[0] = X0c; tp.p[1] = T0_1;
        k_chebgate<u16, 10, 2><<<gv, 256, 0, stream>>>(tp, Wp, b4, H0, N, 16, 128);
    }
    // ---- layer 1: VALU, K=3, Fin=16, F=32 ----
    {
        k_pack_w<<<(48 * 128 + 255) / 256, 256, 0, stream>>>(
            (const float*)d_in[18], (const float*)d_in[26], (const float*)d_in[30], Wp, 48, 32, 128);
        k_pack_b<<<1, 256, 0, stream>>>(
            (const float*)d_in[19], (const float*)d_in[20], (const float*)d_in[21],
            (const float*)d_in[27], (const float*)d_in[28], (const float*)d_in[29],
            (const float*)d_in[31], (const float*)d_in[32], (const float*)d_in[33], b4, 32, 128);
        k_spmv<16><<<g8, bs8, 0, stream>>>(H0, nullptr, T1_1, row_ptr, edges, N, 1.f);
        k_spmv<16><<<g8, bs8, 0, stream>>>(T1_1, H0, T1_2, row_ptr, edges, N, 2.f);
        TP tp; tp.p[0] = H0; tp.p[1] = T1_1; tp.p[2] = T1_2;
        k_chebgate<u16, 16, 3><<<gv, 256, 0, stream>>>(tp, Wp, b4, L2T[0], N, 32, 128);
    }
    // ---- layer 2: MFMA, K=4, Fin=32, F=64 ----
    {
        k_pack_wt<<<(3 * 64 * 128 + 255) / 256, 256, 0, stream>>>(
            (const float*)d_in[34], (const float*)d_in[42], (const float*)d_in[46], Wt, 128, 32, 64, 64);
        k_pack_b3<<<1, 256, 0, stream>>>(
            (const float*)d_in[35], (const float*)d_in[36], (const float*)d_in[37],
            (const float*)d_in[43], (const float*)d_in[44], (const float*)d_in[45],
            (const float*)d_in[47], (const float*)d_in[48], (const float*)d_in[49], b3, 64, 64);
        k_spmv<32><<<g16, bs16, 0, stream>>>(L2T[0], nullptr, L2T[1], row_ptr, edges, N, 1.f);
        k_spmv<32><<<g16, bs16, 0, stream>>>(L2T[1], L2T[0], L2T[2], row_ptr, edges, N, 2.f);
        k_spmv<32><<<g16, bs16, 0, stream>>>(L2T[2], L2T[1], L2T[3], row_ptr, edges, N, 2.f);
        TP tp; for (int t = 0; t < 4; t++) tp.p[t] = L2T[t];
        k_chebgate_mfma<32, 4, 64, 2><<<rb * 2, 256, 0, stream>>>(tp, Wt, b3, L3T[0], N, 64, 64);
    }
    // ---- layer 3: MFMA + fused final projection, K=5, Fin=64, F=152 ----
    {
        k_pack_wt<<<(3 * 160 * 320 + 255) / 256, 256, 0, stream>>>(
            (const float*)d_in[50], (const float*)d_in[58], (const float*)d_in[62], Wt, 320, 64, 152, 160);
        k_pack_b3<<<2, 256, 0, stream>>>(
            (const float*)d_in[51], (const float*)d_in[52], (const float*)d_in[53],
            (const float*)d_in[59], (const float*)d_in[60], (const float*)d_in[61],
            (const float*)d_in[63], (const float*)d_in[64], (const float*)d_in[65], b3, 152, 160);
        k_spmv<64><<<g32, bs32, 0, stream>>>(L3T[0], nullptr, L3T[1], row_ptr, edges, N, 1.f);
        k_spmv<64><<<g32, bs32, 0, stream>>>(L3T[1], L3T[0], L3T[2], row_ptr, edges, N, 2.f);
        k_spmv<64><<<g32, bs32, 0, stream>>>(L3T[2], L3T[1], L3T[3], row_ptr, edges, N, 2.f);
        k_spmv<64><<<g32, bs32, 0, stream>>>(L3T[3], L3T[2], L3T[4], row_ptr, edges, N, 2.f);
        TP tp; for (int t = 0; t < 5; t++) tp.p[t] = L3T[t];
        k_chebgate_mfma_fused<64, 5, 160, 5><<<rb * 5, 256, 0, stream>>>(
            tp, Wt, b3, (const float*)d_in[66], part, N, 152);
    }

    k_smax<<<gN, 256, 0, stream>>>(part, (const float*)d_in[67], (float*)d_out, N, 5);
}